// Round 6
// baseline (1104.550 us; speedup 1.0000x reference)
//
#include <hip/hip_runtime.h>

// Problem constants: B=4, N=128, T=512, K=30 bands. All I/O fp32.
typedef const float* fp;
typedef unsigned short u16;
typedef __attribute__((ext_vector_type(8))) short bf16x8;   // 8 bf16 = 4 VGPRs
typedef __attribute__((ext_vector_type(4))) float f32x4;

__device__ __forceinline__ u16 f2b(float f) {
  union { float f; unsigned u; } a; a.f = f;
  unsigned u = a.u;
  u += 0x7fffu + ((u >> 16) & 1u);   // RNE
  return (u16)(u >> 16);
}
// split fp32 into hi (truncated bf16) + lo (RNE bf16 of exact remainder)
__device__ __forceinline__ void splitf(float x, u16& h, u16& l) {
  union { float f; unsigned u; } a; a.f = x;
  unsigned hu = a.u & 0xFFFF0000u;
  h = (u16)(hu >> 16);
  union { unsigned u; float f; } b; b.u = hu;
  l = f2b(x - b.f);
}

// ---------------- Stage 0: adjacency mask ----------------
__global__ __launch_bounds__(64) void k_adj(fp be, float* mask) {
  __shared__ float e[30][65];
  __shared__ float sim[30][33];
  __shared__ float A[30][33];
  int tid = threadIdx.x;
  for (int idx = tid; idx < 30 * 64; idx += 64) e[idx / 64][idx % 64] = be[idx];
  __syncthreads();
  if (tid < 30) {
    float s = 0.f;
    for (int d = 0; d < 64; d++) s += e[tid][d] * e[tid][d];
    float sc = 1.0f / (sqrtf(s) + 1e-8f);
    for (int d = 0; d < 64; d++) e[tid][d] *= sc;
  }
  __syncthreads();
  if (tid < 30) {
    for (int j = 0; j < 30; j++) {
      float s = 0.f;
      for (int d = 0; d < 64; d++) s += e[tid][d] * e[j][d];
      sim[tid][j] = s;
    }
    for (int j = 0; j < 30; j++) A[tid][j] = 0.f;
  }
  __syncthreads();
  if (tid < 30) {
    unsigned used = 0;
    for (int t = 0; t < 5; t++) {
      float best = -1e30f; int bi = 0;
      for (int j = 0; j < 30; j++)
        if (!((used >> j) & 1u) && sim[tid][j] > best) { best = sim[tid][j]; bi = j; }
      A[tid][bi] = best; used |= 1u << bi;
    }
  }
  __syncthreads();
  for (int idx = tid; idx < 900; idx += 64) {
    int i = idx / 30, j = idx % 30;
    float s = A[i][j] + A[j][i];
    mask[idx] = (s != 0.0f) ? 1.0f : 0.0f;
  }
}

// ---------------- Prep: transpose+split band weights into B-frag layout -------
// which 0..2 -> wqkT[kb][m 0..319][n]; which 3 -> woT[kb][n 0..127][d 0..63]
__global__ __launch_bounds__(256) void k_wt_band(fp Wq, fp Wk, fp Wv, fp Wo,
                                                 u16* wh, u16* wl, u16* woh, u16* wol) {
  int kb = blockIdx.x, which = blockIdx.y;
  __shared__ float wsb[128][129];
  int tid = threadIdx.x;
  if (which == 3) {
    fp src = Wo + kb * 8192;          // [64][128]
    for (int i = tid; i < 8192; i += 256) {
      int d = i >> 7, n = i & 127;
      wsb[n][d] = src[i];
    }
    __syncthreads();
    long base = (long)kb * 8192;
    for (int o = tid; o < 8192; o += 256) {
      u16 h, l; splitf(wsb[o >> 6][o & 63], h, l);
      woh[base + o] = h; wol[base + o] = l;
    }
    return;
  }
  int M = (which == 2) ? 64 : 128;
  int sh = (which == 2) ? 6 : 7;
  fp src = (which == 0) ? (Wq + kb * 16384) : (which == 1) ? (Wk + kb * 16384) : (Wv + kb * 8192);
  for (int i = tid; i < 128 * M; i += 256) {
    int n = i >> sh, m = i & (M - 1);
    wsb[n][m] = src[i];
  }
  __syncthreads();
  long base = (long)kb * 40960 + which * 16384;
  for (int o = tid; o < 128 * M; o += 256) {
    int m = o >> 7, n = o & 127;
    u16 h, l; splitf(wsb[n][m], h, l);
    wh[base + m * 128 + n] = h; wl[base + m * 128 + n] = l;
  }
}

// gwT[m 0..511][n]: gWq 0..127, gWk 128..255, gWv 256..383, gWo 384..511
__global__ __launch_bounds__(256) void k_wt_graph(fp gWq, fp gWk, fp gWv, fp gWo,
                                                  u16* wh, u16* wl) {
  int w = blockIdx.x;
  fp src = (w == 0) ? gWq : (w == 1) ? gWk : (w == 2) ? gWv : gWo;
  __shared__ float wsb[128][129];
  int tid = threadIdx.x;
  for (int i = tid; i < 16384; i += 256) wsb[i >> 7][i & 127] = src[i];
  __syncthreads();
  long base = (long)w * 16384;
  for (int o = tid; o < 16384; o += 256) {
    int m = o >> 7, n = o & 127;
    u16 h, l; splitf(wsb[n][m], h, l);
    wh[base + m * 128 + n] = h; wl[base + m * 128 + n] = l;
  }
}

// ---------------- Stage 1a: QKV projections via MFMA ----------------
__global__ __launch_bounds__(256) void k_qkv(fp x, const u16* wh, const u16* wl,
                                             u16* qh, u16* ql, u16* kh, u16* kl,
                                             u16* vTh, u16* vTl) {
  int kb = blockIdx.z, b = blockIdx.y, t0 = blockIdx.x * 64;
  int tid = threadIdx.x;
  int wave = tid >> 6, lane = tid & 63, l15 = lane & 15, quad = lane >> 4;
  __shared__ u16 xs_h[64 * 136];
  __shared__ u16 xs_l[64 * 136];
  for (int i = tid; i < 8192; i += 256) {
    int tl = i >> 7, n = i & 127;
    float v = x[((long)(b * 128 + n) * 512 + t0 + tl) * 30 + kb];
    u16 h, l; splitf(v, h, l);
    xs_h[tl * 136 + n] = h; xs_l[tl * 136 + n] = l;
  }
  __syncthreads();
  int arow = wave * 16 + l15;
  bf16x8 Ah[4], Al[4];
#pragma unroll
  for (int kc = 0; kc < 4; kc++) {
    Ah[kc] = *(const bf16x8*)(xs_h + arow * 136 + kc * 32 + quad * 8);
    Al[kc] = *(const bf16x8*)(xs_l + arow * 136 + kc * 32 + quad * 8);
  }
  int pair = kb * 4 + b;
  const u16* wbh = wh + (long)kb * 40960;
  const u16* wbl = wl + (long)kb * 40960;
  for (int c = 0; c < 20; c++) {
    f32x4 d = {0.f, 0.f, 0.f, 0.f};
#pragma unroll
    for (int kc = 0; kc < 4; kc++) {
      long boff = (long)(c * 16 + l15) * 128 + kc * 32 + quad * 8;
      bf16x8 Bh = *(const bf16x8*)(wbh + boff);
      bf16x8 Bl = *(const bf16x8*)(wbl + boff);
      d = __builtin_amdgcn_mfma_f32_16x16x32_bf16(Ah[kc], Bh, d, 0, 0, 0);
      d = __builtin_amdgcn_mfma_f32_16x16x32_bf16(Ah[kc], Bl, d, 0, 0, 0);
      d = __builtin_amdgcn_mfma_f32_16x16x32_bf16(Al[kc], Bh, d, 0, 0, 0);
    }
    if (c < 8) {
      int m = c * 16 + l15;
#pragma unroll
      for (int r = 0; r < 4; r++) {
        int trow = t0 + wave * 16 + quad * 4 + r;
        u16 h, l; splitf(d[r], h, l);
        long o = ((long)pair * 512 + trow) * 128 + m;
        qh[o] = h; ql[o] = l;
      }
    } else if (c < 16) {
      int m = (c - 8) * 16 + l15;
#pragma unroll
      for (int r = 0; r < 4; r++) {
        int trow = t0 + wave * 16 + quad * 4 + r;
        u16 h, l; splitf(d[r], h, l);
        long o = ((long)pair * 512 + trow) * 128 + m;
        kh[o] = h; kl[o] = l;
      }
    } else {
      int dcol = (c - 16) * 16 + l15;
#pragma unroll
      for (int r = 0; r < 4; r++) {
        int trow = t0 + wave * 16 + quad * 4 + r;
        u16 h, l; splitf(d[r], h, l);
        long o = ((long)pair * 64 + dcol) * 512 + trow;
        vTh[o] = h; vTl[o] = l;
      }
    }
  }
}

// ---------------- Stage 1b: fused flash kernel (1D grid, pair-XCD swizzle) ----
__global__ __launch_bounds__(256) void k_flash(const u16* qh, const u16* ql,
                                               const u16* kh, const u16* kl,
                                               const u16* vTh, const u16* vTl,
                                               float* rowstats,
                                               u16* ob1h, u16* ob1l, u16* ob2h, u16* ob2l) {
  int bid = blockIdx.x;
  int pair = bid % 120;              // XCD = pair % 8 (120 % 8 == 0)
  int t0 = (bid / 120) * 16;
  int tid = threadIdx.x;
  int wave = tid >> 6, lane = tid & 63;
  int l15 = lane & 15, quad = lane >> 4;

  __shared__ float fbig[8704];
  __shared__ float st[2][16][4][4];
  __shared__ float fin[2][16][2];

  const long pb = (long)pair * 512 * 128;
  const u16* qhb = qh + pb; const u16* qlb = ql + pb;
  const u16* khb = kh + pb; const u16* klb = kl + pb;

  float sc[2][8][4];
#pragma unroll
  for (int h = 0; h < 2; h++) {
    long abase = (long)(t0 + l15) * 128 + h * 64 + quad * 8;
    bf16x8 Ah0 = *(const bf16x8*)(qhb + abase);
    bf16x8 Ah1 = *(const bf16x8*)(qhb + abase + 32);
    bf16x8 Al0 = *(const bf16x8*)(qlb + abase);
    bf16x8 Al1 = *(const bf16x8*)(qlb + abase + 32);
#pragma unroll
    for (int ct = 0; ct < 8; ct++) {
      int scol = wave * 128 + ct * 16 + l15;
      long bbase = (long)scol * 128 + h * 64 + quad * 8;
      bf16x8 Bh0 = *(const bf16x8*)(khb + bbase);
      bf16x8 Bh1 = *(const bf16x8*)(khb + bbase + 32);
      bf16x8 Bl0 = *(const bf16x8*)(klb + bbase);
      bf16x8 Bl1 = *(const bf16x8*)(klb + bbase + 32);
      f32x4 d = {0.f, 0.f, 0.f, 0.f};
      d = __builtin_amdgcn_mfma_f32_16x16x32_bf16(Ah0, Bh0, d, 0, 0, 0);
      d = __builtin_amdgcn_mfma_f32_16x16x32_bf16(Ah1, Bh1, d, 0, 0, 0);
      d = __builtin_amdgcn_mfma_f32_16x16x32_bf16(Ah0, Bl0, d, 0, 0, 0);
      d = __builtin_amdgcn_mfma_f32_16x16x32_bf16(Ah1, Bl1, d, 0, 0, 0);
      d = __builtin_amdgcn_mfma_f32_16x16x32_bf16(Al0, Bh0, d, 0, 0, 0);
      d = __builtin_amdgcn_mfma_f32_16x16x32_bf16(Al1, Bh1, d, 0, 0, 0);
#pragma unroll
      for (int r = 0; r < 4; r++) sc[h][ct][r] = d[r] * 0.25f;
    }
  }
#pragma unroll
  for (int h = 0; h < 2; h++)
#pragma unroll
    for (int r = 0; r < 4; r++) {
      float m = -1e30f, mnv = 1e30f;
#pragma unroll
      for (int ct = 0; ct < 8; ct++) { m = fmaxf(m, sc[h][ct][r]); mnv = fminf(mnv, sc[h][ct][r]); }
      for (int d = 1; d < 16; d <<= 1) { m = fmaxf(m, __shfl_xor(m, d)); mnv = fminf(mnv, __shfl_xor(mnv, d)); }
      float z = 0.f, s2 = 0.f;
#pragma unroll
      for (int ct = 0; ct < 8; ct++) { float e = expf(sc[h][ct][r] - m); z += e; s2 += e * e; }
      for (int d = 1; d < 16; d <<= 1) { z += __shfl_xor(z, d); s2 += __shfl_xor(s2, d); }
      if (l15 == 0) {
        st[h][quad * 4 + r][wave][0] = m;  st[h][quad * 4 + r][wave][1] = z;
        st[h][quad * 4 + r][wave][2] = s2; st[h][quad * 4 + r][wave][3] = mnv;
      }
    }
  __syncthreads();
  if (tid < 32) {
    int row = tid & 15, h = tid >> 4;
    float Mf = -1e30f, mnf = 1e30f;
    for (int w = 0; w < 4; w++) { Mf = fmaxf(Mf, st[h][row][w][0]); mnf = fminf(mnf, st[h][row][w][3]); }
    float Z = 0.f, S2 = 0.f;
    for (int w = 0; w < 4; w++) {
      float f = expf(st[h][row][w][0] - Mf);
      Z += st[h][row][w][1] * f; S2 += st[h][row][w][2] * f * f;
    }
    float* o = rowstats + ((long)pair * 512 + t0 + row) * 8 + h * 4;
    o[0] = Mf; o[1] = Z; o[2] = S2; o[3] = mnf;
    fin[h][row][0] = Mf; fin[h][row][1] = 1.0f / Z;
  }
  __syncthreads();
  u16* pbuf = (u16*)fbig;   // [h][wave][row16][136]
#pragma unroll
  for (int h = 0; h < 2; h++)
#pragma unroll
    for (int r = 0; r < 4; r++) {
      int row = quad * 4 + r;
      float Mf = fin[h][row][0], iZ = fin[h][row][1];
#pragma unroll
      for (int ct = 0; ct < 8; ct++) {
        float p = expf(sc[h][ct][r] - Mf) * iZ;
        pbuf[((h * 4 + wave) * 16 + row) * 136 + ct * 16 + l15] = f2b(p);
      }
    }
  __syncthreads();
  f32x4 acc[2][4];
#pragma unroll
  for (int h = 0; h < 2; h++)
#pragma unroll
    for (int nt = 0; nt < 4; nt++) acc[h][nt] = {0.f, 0.f, 0.f, 0.f};
  const u16* vThb = vTh + (long)pair * 64 * 512;
  const u16* vTlb = vTl + (long)pair * 64 * 512;
#pragma unroll
  for (int kc = 0; kc < 4; kc++) {
    int sbase = wave * 128 + kc * 32 + quad * 8;
    bf16x8 A0 = *(const bf16x8*)(pbuf + ((0 * 4 + wave) * 16 + l15) * 136 + kc * 32 + quad * 8);
    bf16x8 A1 = *(const bf16x8*)(pbuf + ((1 * 4 + wave) * 16 + l15) * 136 + kc * 32 + quad * 8);
#pragma unroll
    for (int nt = 0; nt < 4; nt++) {
      long vo = (long)(nt * 16 + l15) * 512 + sbase;
      bf16x8 Vh = *(const bf16x8*)(vThb + vo);
      bf16x8 Vl = *(const bf16x8*)(vTlb + vo);
      acc[0][nt] = __builtin_amdgcn_mfma_f32_16x16x32_bf16(A0, Vh, acc[0][nt], 0, 0, 0);
      acc[0][nt] = __builtin_amdgcn_mfma_f32_16x16x32_bf16(A0, Vl, acc[0][nt], 0, 0, 0);
      acc[1][nt] = __builtin_amdgcn_mfma_f32_16x16x32_bf16(A1, Vh, acc[1][nt], 0, 0, 0);
      acc[1][nt] = __builtin_amdgcn_mfma_f32_16x16x32_bf16(A1, Vl, acc[1][nt], 0, 0, 0);
    }
  }
  __syncthreads();
  float* obr = fbig; // [wave][h][row16][68]
#pragma unroll
  for (int h = 0; h < 2; h++)
#pragma unroll
    for (int nt = 0; nt < 4; nt++)
#pragma unroll
      for (int r = 0; r < 4; r++)
        obr[((wave * 2 + h) * 16 + quad * 4 + r) * 68 + nt * 16 + l15] = acc[h][nt][r];
  __syncthreads();
  for (int i = tid; i < 2048; i += 256) {
    int h = i >> 10, row = (i >> 6) & 15, d = i & 63;
    float s = 0.f;
    for (int w = 0; w < 4; w++) s += obr[((w * 2 + h) * 16 + row) * 68 + d];
    u16 hh, ll; splitf(s, hh, ll);
    long o = ((long)pair * 512 + t0 + row) * 64 + d;
    if (h == 0) { ob1h[o] = hh; ob1l[o] = ll; }
    else        { ob2h[o] = hh; ob2l[o] = ll; }
  }
}

// ---------------- Stage 1c: lambda MLP ----------------
__global__ __launch_bounds__(64) void k_lam(const float* rowstats, fp lw1, fp lb1,
                                            fp lw2, fp lb2, float* lam) {
  int pair = blockIdx.x; int kb = pair >> 2;
  int tid = threadIdx.x;
  const float* rs = rowstats + (long)pair * 512 * 8;
  float mx1 = -1e30f, mn1 = 1e30f, ss1 = 0.f, mx2 = -1e30f, mn2 = 1e30f, ss2 = 0.f;
  for (int j = 0; j < 8; j++) {
    const float* rr = rs + (long)(j * 64 + tid) * 8;
    float M1 = rr[0], Z1 = rr[1], S21 = rr[2], m1 = rr[3];
    float M2 = rr[4], Z2 = rr[5], S22 = rr[6], m2 = rr[7];
    mx1 = fmaxf(mx1, 1.0f / Z1); mn1 = fminf(mn1, expf(m1 - M1) / Z1); ss1 += S21 / (Z1 * Z1);
    mx2 = fmaxf(mx2, 1.0f / Z2); mn2 = fminf(mn2, expf(m2 - M2) / Z2); ss2 += S22 / (Z2 * Z2);
  }
  __shared__ float red[64][8];
  red[tid][0] = mx1; red[tid][1] = mn1; red[tid][2] = ss1;
  red[tid][3] = mx2; red[tid][4] = mn2; red[tid][5] = ss2;
  __syncthreads();
  if (tid == 0) {
    for (int e = 1; e < 64; e++) {
      mx1 = fmaxf(mx1, red[e][0]); mn1 = fminf(mn1, red[e][1]); ss1 += red[e][2];
      mx2 = fmaxf(mx2, red[e][3]); mn2 = fminf(mn2, red[e][4]); ss2 += red[e][5];
    }
    const float mean = 1.0f / 512.0f;
    const float n = 262144.0f;
    float v1 = (ss1 - n * mean * mean) / (n - 1.0f); float sd1 = sqrtf(fmaxf(v1, 0.f));
    float v2 = (ss2 - n * mean * mean) / (n - 1.0f); float sd2 = sqrtf(fmaxf(v2, 0.f));
    float stv[8] = { mean, sd1, mx1, mn1, mean, sd2, mx2, mn2 };
    float acc = lb2[kb];
    for (int o = 0; o < 16; o++) {
      float h = lb1[kb * 16 + o];
      for (int i = 0; i < 8; i++) h += stv[i] * lw1[(kb * 8 + i) * 16 + o];
      h = fmaxf(h, 0.f);
      acc += h * lw2[kb * 16 + o];
    }
    lam[pair] = 1.0f / (1.0f + expf(-acc));
  }
}

// ---------------- Stage 1d: epilogue h1 = ob1@Wo - lam*(ob2@Wo) + bo (MFMA) ---
__global__ __launch_bounds__(256) void k_ep(const u16* ob1h, const u16* ob1l,
                                            const u16* ob2h, const u16* ob2l,
                                            const float* lam, const u16* woh, const u16* wol,
                                            fp bo, u16* h1h, u16* h1l) {
  int pair = blockIdx.y; int kb = pair >> 2, b = pair & 3;
  int t0 = blockIdx.x * 16;
  int tid = threadIdx.x;
  int wave = tid >> 6, lane = tid & 63, l15 = lane & 15, quad = lane >> 4;
  float lv = lam[pair];
  long ab = ((long)pair * 512 + t0 + l15) * 64 + quad * 8;
  bf16x8 A1h[2], A1l[2], A2h[2], A2l[2];
#pragma unroll
  for (int kc = 0; kc < 2; kc++) {
    A1h[kc] = *(const bf16x8*)(ob1h + ab + kc * 32);
    A1l[kc] = *(const bf16x8*)(ob1l + ab + kc * 32);
    A2h[kc] = *(const bf16x8*)(ob2h + ab + kc * 32);
    A2l[kc] = *(const bf16x8*)(ob2l + ab + kc * 32);
  }
  const u16* wbh = woh + (long)kb * 8192;
  const u16* wbl = wol + (long)kb * 8192;
#pragma unroll
  for (int cc = 0; cc < 2; cc++) {
    int c = wave * 2 + cc;
    f32x4 d1 = {0.f, 0.f, 0.f, 0.f}, d2 = {0.f, 0.f, 0.f, 0.f};
#pragma unroll
    for (int kc = 0; kc < 2; kc++) {
      long boff = (long)(c * 16 + l15) * 64 + kc * 32 + quad * 8;
      bf16x8 Bh = *(const bf16x8*)(wbh + boff);
      bf16x8 Bl = *(const bf16x8*)(wbl + boff);
      d1 = __builtin_amdgcn_mfma_f32_16x16x32_bf16(A1h[kc], Bh, d1, 0, 0, 0);
      d1 = __builtin_amdgcn_mfma_f32_16x16x32_bf16(A1h[kc], Bl, d1, 0, 0, 0);
      d1 = __builtin_amdgcn_mfma_f32_16x16x32_bf16(A1l[kc], Bh, d1, 0, 0, 0);
      d2 = __builtin_amdgcn_mfma_f32_16x16x32_bf16(A2h[kc], Bh, d2, 0, 0, 0);
      d2 = __builtin_amdgcn_mfma_f32_16x16x32_bf16(A2h[kc], Bl, d2, 0, 0, 0);
      d2 = __builtin_amdgcn_mfma_f32_16x16x32_bf16(A2l[kc], Bh, d2, 0, 0, 0);
    }
    int n = c * 16 + l15;
    float bias = bo[kb * 128 + n];
#pragma unroll
    for (int r = 0; r < 4; r++) {
      int t = t0 + quad * 4 + r;
      float val = d1[r] - lv * d2[r] + bias;
      u16 h, l; splitf(val, h, l);
      long o = ((long)(b * 30 + kb) * 512 + t) * 128 + n;
      h1h[o] = h; h1l[o] = l;
    }
  }
}

// ---------------- Stage 2a: combined conv kernel, packed active taps ----------
// layout [g 0..455][no 128][ni 128]; g = packed (kb, tap)
__global__ __launch_bounds__(256) void k_ck(fp fw, fp cw2, fp cw4, fp cw8,
                                            fp cw16, fp cw32, u16* ckh, u16* ckl) {
  long idx = (long)blockIdx.x * 256 + threadIdx.x;
  int ni = idx & 127;
  int no = (idx >> 7) & 127;
  int g  = (int)(idx >> 14);
  int kb, r;
  if (g < 192)      { kb = g >> 5;                r = g & 31; }
  else if (g < 336) { int gg = g - 192; kb = 6 + (gg >> 4);  r = 8 + (gg & 15); }
  else              { int gg = g - 336; kb = 15 + (gg >> 3); r = 12 + (gg & 7); }
  float f0 = fw[kb * 3 + 0], f1 = fw[kb * 3 + 1], f2 = fw[kb * 3 + 2];
  float mx = fmaxf(f0, fmaxf(f1, f2));
  float e0 = expf(f0 - mx), e1 = expf(f1 - mx), e2 = expf(f2 - mx);
  float zi = 1.0f / (e0 + e1 + e2);
  float sw[3] = { e0 * zi, e1 * zi, e2 * zi };
  int sbase; fp cws[3];
  if (kb < 6)       { sbase = 8; cws[0] = cw8;  cws[1] = cw16; cws[2] = cw32; }
  else if (kb < 15) { sbase = 4; cws[0] = cw4;  cws[1] = cw8;  cws[2] = cw16; }
  else              { sbase = 2; cws[0] = cw2;  cws[1] = cw4;  cws[2] = cw8;  }
  float val = 0.f;
  int rs = r - 16;
#pragma unroll
  for (int j = 0; j < 3; j++) {
    int s = sbase << j;
    int tau = rs + (s >> 1);
    if (tau >= 0 && tau < s) val += sw[j] * cws[j][((long)no * 128 + ni) * s + tau];
  }
  u16 h, l; splitf(val, h, l);
  ckh[idx] = h; ckl[idx] = l;
}

// ---------------- Stage 2b: per-band conv via MFMA (kb-XCD swizzle) -----------
__global__ __launch_bounds__(256) void k_conv(const u16* h1h, const u16* h1l,
                                              const u16* ckh, const u16* ckl, fp fw,
                                              fp cb2, fp cb4, fp cb8, fp cb16,
                                              fp cb32, u16* h2h, u16* h2l) {
  int bid = blockIdx.x;
  int kb = bid & 31;
  if (kb >= 30) return;               // XCD = kb % 8
  int rem = bid >> 5;
  int b = rem & 3, t0 = (rem >> 2) * 64;
  int tid = threadIdx.x;
  int wave = tid >> 6, lane = tid & 63, l15 = lane & 15, quad = lane >> 4;
  __shared__ u16 xs_h[96 * 136];
  __shared__ u16 xs_l[96 * 136];
  const u16* xrh = h1h + (long)(b * 30 + kb) * 512 * 128;
  const u16* xrl = h1l + (long)(b * 30 + kb) * 512 * 128;
  bf16x8 zero8 = {0, 0, 0, 0, 0, 0, 0, 0};
  for (int i = tid; i < 1536; i += 256) {
    int row = i >> 4, c8 = (i & 15) << 3;
    int t = t0 - 16 + row;
    bf16x8 vh = zero8, vl = zero8;
    if (t >= 0 && t < 512) {
      vh = *(const bf16x8*)(xrh + (long)t * 128 + c8);
      vl = *(const bf16x8*)(xrl + (long)t * 128 + c8);
    }
    *(bf16x8*)(xs_h + row * 136 + c8) = vh;
    *(bf16x8*)(xs_l + row * 136 + c8) = vl;
  }
  float f0 = fw[kb * 3 + 0], f1 = fw[kb * 3 + 1], f2 = fw[kb * 3 + 2];
  float mx = fmaxf(f0, fmaxf(f1, f2));
  float e0 = expf(f0 - mx), e1 = expf(f1 - mx), e2 = expf(f2 - mx);
  float zi = 1.0f / (e0 + e1 + e2);
  float sw0 = e0 * zi, sw1 = e1 * zi, sw2 = e2 * zi;
  int rlo, rhi, gbase; fp c0, c1, c2;
  if (kb < 6)       { rlo = 0;  rhi = 32; gbase = kb * 32;             c0 = cb8; c1 = cb16; c2 = cb32; }
  else if (kb < 15) { rlo = 8;  rhi = 24; gbase = 192 + (kb - 6) * 16; c0 = cb4; c1 = cb8;  c2 = cb16; }
  else              { rlo = 12; rhi = 20; gbase = 336 + (kb - 15) * 8; c0 = cb2; c1 = cb4;  c2 = cb8;  }
  __syncthreads();
  f32x4 acc[4][2];
#pragma unroll
  for (int mt = 0; mt < 4; mt++) { acc[mt][0] = {0.f,0.f,0.f,0.f}; acc[mt][1] = {0.f,0.f,0.f,0.f}; }
  for (int r = rlo; r < rhi; r++) {
    const u16* wh = ckh + ((long)(gbase + r - rlo) * 128 + wave * 32 + l15) * 128;
    const u16* wl = ckl + ((long)(gbase + r - rlo) * 128 + wave * 32 + l15) * 128;
#pragma unroll
    for (int c = 0; c < 4; c++) {
      int koff = c * 32 + quad * 8;
      bf16x8 Bh0 = *(const bf16x8*)(wh + koff);
      bf16x8 Bh1 = *(const bf16x8*)(wh + 2048 + koff);
      bf16x8 Bl0 = *(const bf16x8*)(wl + koff);
      bf16x8 Bl1 = *(const bf16x8*)(wl + 2048 + koff);
#pragma unroll
      for (int mt = 0; mt < 4; mt++) {
        int arow = mt * 16 + l15 + r;
        bf16x8 Ah = *(const bf16x8*)(xs_h + arow * 136 + koff);
        bf16x8 Al = *(const bf16x8*)(xs_l + arow * 136 + koff);
        acc[mt][0] = __builtin_amdgcn_mfma_f32_16x16x32_bf16(Ah, Bh0, acc[mt][0], 0, 0, 0);
        acc[mt][0] = __builtin_amdgcn_mfma_f32_16x16x32_bf16(Ah, Bl0, acc[mt][0], 0, 0, 0);
        acc[mt][0] = __builtin_amdgcn_mfma_f32_16x16x32_bf16(Al, Bh0, acc[mt][0], 0, 0, 0);
        acc[mt][1] = __builtin_amdgcn_mfma_f32_16x16x32_bf16(Ah, Bh1, acc[mt][1], 0, 0, 0);
        acc[mt][1] = __builtin_amdgcn_mfma_f32_16x16x32_bf16(Ah, Bl1, acc[mt][1], 0, 0, 0);
        acc[mt][1] = __builtin_amdgcn_mfma_f32_16x16x32_bf16(Al, Bh1, acc[mt][1], 0, 0, 0);
      }
    }
  }
  int no0 = wave * 32 + l15;
  float bias0 = sw0 * c0[no0] + sw1 * c1[no0] + sw2 * c2[no0];
  float bias1 = sw0 * c0[no0 + 16] + sw1 * c1[no0 + 16] + sw2 * c2[no0 + 16];
#pragma unroll
  for (int mt = 0; mt < 4; mt++)
#pragma unroll
    for (int reg = 0; reg < 4; reg++) {
      int t = t0 + mt * 16 + quad * 4 + reg;
      long ob = ((long)(b * 512 + t) * 30 + kb) * 128 + no0;
      u16 h, l;
      splitf(acc[mt][0][reg] + bias0, h, l); h2h[ob] = h;      h2l[ob] = l;
      splitf(acc[mt][1][reg] + bias1, h, l); h2h[ob + 16] = h; h2l[ob + 16] = l;
    }
}

// ---------------- Stage 3: fused graph QKV + attention + out GEMM -------------
__global__ __launch_bounds__(256) void k_gattn(const u16* h2h, const u16* h2l,
                                               const u16* gwh, const u16* gwl,
                                               const float* maskw,
                                               fp gbq, fp gbk, fp gbv, fp gbo,
                                               float* out) {
  int m = blockIdx.x; int b = m >> 9; int t = m & 511;
  int tid = threadIdx.x;
  int wave = tid >> 6, lane = tid & 63, l15 = lane & 15, quad = lane >> 4;
  __shared__ float qs[32][136];
  __shared__ float ks[32][136];
  __shared__ float vs[32][136];
  u16* ogs_h = (u16*)&qs[0][0];
  u16* ogs_l = ogs_h + 32 * 136;

  // ---- Phase 1: QKV projection via MFMA ----
  {
    int mtile = wave & 1;
    int c0 = (wave >> 1) * 12;
    long abase0 = (long)m * 30 * 128;
    bf16x8 Ah[4], Al[4];
    bf16x8 zero8 = {0, 0, 0, 0, 0, 0, 0, 0};
    int row = mtile * 16 + l15;
#pragma unroll
    for (int kc = 0; kc < 4; kc++) {
      if (row < 30) {
        Ah[kc] = *(const bf16x8*)(h2h + abase0 + (long)row * 128 + kc * 32 + quad * 8);
        Al[kc] = *(const bf16x8*)(h2l + abase0 + (long)row * 128 + kc * 32 + quad * 8);
      } else { Ah[kc] = zero8; Al[kc] = zero8; }
    }
    for (int cc = 0; cc < 12; cc++) {
      int c = c0 + cc;
      f32x4 d = {0.f, 0.f, 0.f, 0.f};
#pragma unroll
      for (int kc = 0; kc < 4; kc++) {
        long boff = (long)(c * 16 + l15) * 128 + kc * 32 + quad * 8;
        bf16x8 Bh = *(const bf16x8*)(gwh + boff);
        bf16x8 Bl = *(const bf16x8*)(gwl + boff);
        d = __builtin_amdgcn_mfma_f32_16x16x32_bf16(Ah[kc], Bh, d, 0, 0, 0);
        d = __builtin_amdgcn_mfma_f32_16x16x32_bf16(Ah[kc], Bl, d, 0, 0, 0);
        d = __builtin_amdgcn_mfma_f32_16x16x32_bf16(Al[kc], Bh, d, 0, 0, 0);
      }
      int region = c >> 3;
      int ch = (c & 7) * 16 + l15;
      float bias = (region == 0) ? gbq[ch] : (region == 1) ? gbk[ch] : gbv[ch];
      float (*dst)[136] = (region == 0) ? qs : (region == 1) ? ks : vs;
#pragma unroll
      for (int r = 0; r < 4; r++) {
        int rowo = mtile * 16 + quad * 4 + r;
        if (rowo < 30) dst[rowo][ch] = d[r] + bias;
      }
    }
  }
  __syncthreads();

  // ---- Phase 2: 30x30 4-head attention (VALU) ----
  float p[30]; float iZ = 0.f; int hi = 0, ii = 0;
  if (tid < 120) {
    hi = tid / 30; ii = tid % 30;
    int hb = hi * 32;
    float4 qv[8];
#pragma unroll
    for (int dq = 0; dq < 8; dq++) qv[dq] = *(const float4*)&qs[ii][hb + dq * 4];
    float mx = -1e30f;
#pragma unroll
    for (int j = 0; j < 30; j++) {
      float s = 0.f;
      const float4* kr = (const float4*)&ks[j][hb];
#pragma unroll
      for (int dq = 0; dq < 8; dq++) {
        float4 kv = kr[dq];
        s += qv[dq].x * kv.x + qv[dq].y * kv.y + qv[dq].z * kv.z + qv[dq].w * kv.w;
      }
      s *= 0.17677669529663687f;
      p[j] = (maskw[ii * 30 + j] != 0.f) ? s : -1e30f;
      mx = fmaxf(mx, p[j]);
    }
    float Z = 0.f;
#pragma unroll
    for (int j = 0; j < 30; j++) { float e = expf(p[j] - mx); p[j] = e; Z += e; }
    iZ = 1.0f / Z;
  }
  __syncthreads();
  if (tid < 120) {
    int hb = hi * 32;
#pragma unroll
    for (int dq = 0; dq < 8; dq++) {
      float sx = 0.f, sy = 0.f, sz = 0.f, sw2 = 0.f;
#pragma unroll
      for (int j = 0; j < 30; j++) {
        float4 vv = *(const float4*)&vs[j][hb + dq * 4];
        sx += p[j] * vv.x; sy += p[j] * vv.y; sz += p[j] * vv.z; sw2 += p[j] * vv.w;
      }
      float o4[4] = { sx * iZ, sy * iZ, sz * iZ, sw2 * iZ };
#pragma unroll
      for (int cpt = 0; cpt < 4; cpt++) {
        u16 h, l; splitf(o4[cpt], h, l);
        ogs_h[ii * 136 + hb + dq * 4 + cpt] = h;
        ogs_l[ii * 136 + hb + dq * 4 + cpt] = l;
      }
    }
  }
  __syncthreads();

  // ---- Phase 3: out = og @ gWo + gbo via MFMA ----
  {
    int mtile = wave & 1;
    int nc0 = (wave >> 1) * 4;
    int row = mtile * 16 + l15;
    bf16x8 Ah[4], Al[4];
#pragma unroll
    for (int kc = 0; kc < 4; kc++) {
      Ah[kc] = *(const bf16x8*)(ogs_h + row * 136 + kc * 32 + quad * 8);
      Al[kc] = *(const bf16x8*)(ogs_l + row * 136 + kc * 32 + quad * 8);
    }
    for (int cc = 0; cc < 4; cc++) {
      int nchunk = nc0 + cc;
      f32x4 d = {0.f, 0.f, 0.f, 0.f};
#pragma unroll
      for (int kc = 0; kc < 4; kc++) {
        long boff = (long)(384 + nchunk * 16 + l15) * 128 + kc * 32 + quad * 8;
        bf16x8 Bh = *(const bf16x8*)(gwh + boff);
        bf16x8 Bl = *(const bf16x8*)(gwl + boff);
        d = __builtin_amdgcn_mfma_f32_16x16x32_bf16(Ah[kc], Bh, d, 0, 0, 0);
        d = __builtin_amdgcn_mfma_f32_16x16x32_bf16(Ah[kc], Bl, d, 0, 0, 0);
        d = __builtin_amdgcn_mfma_f32_16x16x32_bf16(Al[kc], Bh, d, 0, 0, 0);
      }
      int n = nchunk * 16 + l15;
      float gb = gbo[n];
      long obase = ((long)(b * 128 + n) * 512 + t) * 30;
#pragma unroll
      for (int r = 0; r < 4; r++) {
        int kbo = mtile * 16 + quad * 4 + r;
        if (kbo < 30) out[obase + kbo] = d[r] + gb;
      }
    }
  }
}

extern "C" void kernel_launch(void* const* d_in, const int* in_sizes, int n_in,
                              void* d_out, int out_size, void* d_ws, size_t ws_size,
                              hipStream_t stream) {
  fp x = (fp)d_in[0], Wq = (fp)d_in[1], Wk = (fp)d_in[2], Wv = (fp)d_in[3],
     Wo = (fp)d_in[4], bo = (fp)d_in[5], lw1 = (fp)d_in[6], lb1 = (fp)d_in[7],
     lw2 = (fp)d_in[8], lb2 = (fp)d_in[9],
     cw2 = (fp)d_in[10], cb2 = (fp)d_in[11], cw4 = (fp)d_in[12], cb4 = (fp)d_in[13],
     cw8 = (fp)d_in[14], cb8 = (fp)d_in[15], cw16 = (fp)d_in[16], cb16 = (fp)d_in[17],
     cw32 = (fp)d_in[18], cb32 = (fp)d_in[19], fw = (fp)d_in[20], be = (fp)d_in[21],
     gWq = (fp)d_in[22], gbq = (fp)d_in[23], gWk = (fp)d_in[24], gbk = (fp)d_in[25],
     gWv = (fp)d_in[26], gbv = (fp)d_in[27], gWo = (fp)d_in[28], gbo = (fp)d_in[29];
  (void)in_sizes; (void)n_in; (void)out_size; (void)ws_size;

  float* ws = (float*)d_ws;
  // ---- workspace map (float offsets), race-free stage-ordered aliasing ----
  u16* qh  = (u16*)ws;                          // [120][512][128]
  u16* ql  = (u16*)(ws + 3932160L);
  u16* kh  = (u16*)(ws + 7864320L);
  u16* kl  = (u16*)(ws + 11796480L);
  u16* vTh = (u16*)(ws + 15728640L);            // [120][64][512]
  u16* vTl = (u16*)(ws + 17694720L);
  float* rowstats = ws + 19660800L;             // [120][512][8]
  float* lam      = ws + 20152320L;             // [120]
  u16* wqkT_h = (u16*)(ws + 20152448L);         // [30][320][128]
  u16* wqkT_l = (u16*)(ws + 20766848L);
  u16* gwT_h  = (u16*)(ws + 21381248L);         // [512][128]
  u16* gwT_l  = (u16*)(ws + 21414016L);
  float* maskw = ws + 21446784L;                // [900]
  u16* woT_h = (u16*)(ws + 21447808L);          // [30][128][64]
  u16* woT_l = (u16*)(ws + 21570688L);
  u16* ob1h = (u16*)(ws + 21693568L);           // [120][512][64] each
  u16* ob1l = (u16*)(ws + 23659648L);
  u16* ob2h = (u16*)(ws + 25625728L);
  u16* ob2l = (u16*)(ws + 27591808L);           // ends 29,557,888 (118.2 MB peak)
  u16* h1h = (u16*)ws;                          // over dead qh/ql (after k_flash)
  u16* h1l = (u16*)(ws + 3932160L);
  u16* h2h = (u16*)(ws + 7864320L);             // over dead kh/kl
  u16* h2l = (u16*)(ws + 11796480L);
  u16* ckh = (u16*)(ws + 21693568L);            // over dead ob* (after k_ep)
  u16* ckl = (u16*)(ws + 25429120L);

  k_adj<<<1, 64, 0, stream>>>(be, maskw);
  k_wt_band<<<dim3(30, 4), 256, 0, stream>>>(Wq, Wk, Wv, Wo, wqkT_h, wqkT_l, woT_h, woT_l);
  k_wt_graph<<<4, 256, 0, stream>>>(gWq, gWk, gWv, gWo, gwT_h, gwT_l);
  k_qkv<<<dim3(8, 4, 30), 256, 0, stream>>>(x, wqkT_h, wqkT_l, qh, ql, kh, kl, vTh, vTl);
  k_flash<<<3840, 256, 0, stream>>>(qh, ql, kh, kl, vTh, vTl, rowstats, ob1h, ob1l, ob2h, ob2l);
  k_lam<<<120, 64, 0, stream>>>(rowstats, lw1, lb1, lw2, lb2, lam);
  k_ep<<<dim3(32, 120), 256, 0, stream>>>(ob1h, ob1l, ob2h, ob2l, lam, woT_h, woT_l, bo, h1h, h1l);
  k_ck<<<29184, 256, 0, stream>>>(fw, cw2, cw4, cw8, cw16, cw32, ckh, ckl);
  k_conv<<<1024, 256, 0, stream>>>(h1h, h1l, ckh, ckl, fw, cb2, cb4, cb8, cb16, cb32, h2h, h2l);
  k_gattn<<<2048, 256, 0, stream>>>(h2h, h2l, gwT_h, gwT_l, maskw, gbq, gbk, gbv, gbo, (float*)d_out);
}

// Round 7
// 877.221 us; speedup vs baseline: 1.2591x; 1.2591x over previous
//
#include <hip/hip_runtime.h>

// Problem constants: B=4, N=128, T=512, K=30 bands. All I/O fp32.
typedef const float* fp;
typedef unsigned short u16;
typedef __attribute__((ext_vector_type(8))) short bf16x8;   // 8 bf16 = 4 VGPRs
typedef __attribute__((ext_vector_type(4))) float f32x4;

__device__ __forceinline__ u16 f2b(float f) {
  union { float f; unsigned u; } a; a.f = f;
  unsigned u = a.u;
  u += 0x7fffu + ((u >> 16) & 1u);   // RNE
  return (u16)(u >> 16);
}
// split fp32 into hi (truncated bf16) + lo (RNE bf16 of exact remainder)
__device__ __forceinline__ void splitf(float x, u16& h, u16& l) {
  union { float f; unsigned u; } a; a.f = x;
  unsigned hu = a.u & 0xFFFF0000u;
  h = (u16)(hu >> 16);
  union { unsigned u; float f; } b; b.u = hu;
  l = f2b(x - b.f);
}

// ---------------- Stage 0: adjacency mask ----------------
__global__ __launch_bounds__(64) void k_adj(fp be, float* mask) {
  __shared__ float e[30][65];
  __shared__ float sim[30][33];
  __shared__ float A[30][33];
  int tid = threadIdx.x;
  for (int idx = tid; idx < 30 * 64; idx += 64) e[idx / 64][idx % 64] = be[idx];
  __syncthreads();
  if (tid < 30) {
    float s = 0.f;
    for (int d = 0; d < 64; d++) s += e[tid][d] * e[tid][d];
    float sc = 1.0f / (sqrtf(s) + 1e-8f);
    for (int d = 0; d < 64; d++) e[tid][d] *= sc;
  }
  __syncthreads();
  if (tid < 30) {
    for (int j = 0; j < 30; j++) {
      float s = 0.f;
      for (int d = 0; d < 64; d++) s += e[tid][d] * e[j][d];
      sim[tid][j] = s;
    }
    for (int j = 0; j < 30; j++) A[tid][j] = 0.f;
  }
  __syncthreads();
  if (tid < 30) {
    unsigned used = 0;
    for (int t = 0; t < 5; t++) {
      float best = -1e30f; int bi = 0;
      for (int j = 0; j < 30; j++)
        if (!((used >> j) & 1u) && sim[tid][j] > best) { best = sim[tid][j]; bi = j; }
      A[tid][bi] = best; used |= 1u << bi;
    }
  }
  __syncthreads();
  for (int idx = tid; idx < 900; idx += 64) {
    int i = idx / 30, j = idx % 30;
    float s = A[i][j] + A[j][i];
    mask[idx] = (s != 0.0f) ? 1.0f : 0.0f;
  }
}

// ---------------- Prep: transpose+split band weights into B-frag layout -------
// which 0..2 -> wqkT[kb][m 0..319][n]; which 3 -> woT[kb][n 0..127][d 0..63]
__global__ __launch_bounds__(256) void k_wt_band(fp Wq, fp Wk, fp Wv, fp Wo,
                                                 u16* wh, u16* wl, u16* woh, u16* wol) {
  int kb = blockIdx.x, which = blockIdx.y;
  __shared__ float wsb[128][129];
  int tid = threadIdx.x;
  if (which == 3) {
    fp src = Wo + kb * 8192;          // [64][128]
    for (int i = tid; i < 8192; i += 256) {
      int d = i >> 7, n = i & 127;
      wsb[n][d] = src[i];
    }
    __syncthreads();
    long base = (long)kb * 8192;
    for (int o = tid; o < 8192; o += 256) {
      u16 h, l; splitf(wsb[o >> 6][o & 63], h, l);
      woh[base + o] = h; wol[base + o] = l;
    }
    return;
  }
  int M = (which == 2) ? 64 : 128;
  int sh = (which == 2) ? 6 : 7;
  fp src = (which == 0) ? (Wq + kb * 16384) : (which == 1) ? (Wk + kb * 16384) : (Wv + kb * 8192);
  for (int i = tid; i < 128 * M; i += 256) {
    int n = i >> sh, m = i & (M - 1);
    wsb[n][m] = src[i];
  }
  __syncthreads();
  long base = (long)kb * 40960 + which * 16384;
  for (int o = tid; o < 128 * M; o += 256) {
    int m = o >> 7, n = o & 127;
    u16 h, l; splitf(wsb[n][m], h, l);
    wh[base + m * 128 + n] = h; wl[base + m * 128 + n] = l;
  }
}

// gwT[m 0..511][n]: gWq 0..127, gWk 128..255, gWv 256..383, gWo 384..511
__global__ __launch_bounds__(256) void k_wt_graph(fp gWq, fp gWk, fp gWv, fp gWo,
                                                  u16* wh, u16* wl) {
  int w = blockIdx.x;
  fp src = (w == 0) ? gWq : (w == 1) ? gWk : (w == 2) ? gWv : gWo;
  __shared__ float wsb[128][129];
  int tid = threadIdx.x;
  for (int i = tid; i < 16384; i += 256) wsb[i >> 7][i & 127] = src[i];
  __syncthreads();
  long base = (long)w * 16384;
  for (int o = tid; o < 16384; o += 256) {
    int m = o >> 7, n = o & 127;
    u16 h, l; splitf(wsb[n][m], h, l);
    wh[base + m * 128 + n] = h; wl[base + m * 128 + n] = l;
  }
}

// ---------------- Stage 1a: QKV projections via MFMA ----------------
__global__ __launch_bounds__(256) void k_qkv(fp x, const u16* wh, const u16* wl,
                                             u16* qh, u16* ql, u16* kh, u16* kl,
                                             u16* vTh, u16* vTl) {
  int kb = blockIdx.z, b = blockIdx.y, t0 = blockIdx.x * 64;
  int tid = threadIdx.x;
  int wave = tid >> 6, lane = tid & 63, l15 = lane & 15, quad = lane >> 4;
  __shared__ u16 xs_h[64 * 136];
  __shared__ u16 xs_l[64 * 136];
  for (int i = tid; i < 8192; i += 256) {
    int tl = i >> 7, n = i & 127;
    float v = x[((long)(b * 128 + n) * 512 + t0 + tl) * 30 + kb];
    u16 h, l; splitf(v, h, l);
    xs_h[tl * 136 + n] = h; xs_l[tl * 136 + n] = l;
  }
  __syncthreads();
  int arow = wave * 16 + l15;
  bf16x8 Ah[4], Al[4];
#pragma unroll
  for (int kc = 0; kc < 4; kc++) {
    Ah[kc] = *(const bf16x8*)(xs_h + arow * 136 + kc * 32 + quad * 8);
    Al[kc] = *(const bf16x8*)(xs_l + arow * 136 + kc * 32 + quad * 8);
  }
  int pair = kb * 4 + b;
  const u16* wbh = wh + (long)kb * 40960;
  const u16* wbl = wl + (long)kb * 40960;
  for (int c = 0; c < 20; c++) {
    f32x4 d = {0.f, 0.f, 0.f, 0.f};
#pragma unroll
    for (int kc = 0; kc < 4; kc++) {
      long boff = (long)(c * 16 + l15) * 128 + kc * 32 + quad * 8;
      bf16x8 Bh = *(const bf16x8*)(wbh + boff);
      bf16x8 Bl = *(const bf16x8*)(wbl + boff);
      d = __builtin_amdgcn_mfma_f32_16x16x32_bf16(Ah[kc], Bh, d, 0, 0, 0);
      d = __builtin_amdgcn_mfma_f32_16x16x32_bf16(Ah[kc], Bl, d, 0, 0, 0);
      d = __builtin_amdgcn_mfma_f32_16x16x32_bf16(Al[kc], Bh, d, 0, 0, 0);
    }
    if (c < 8) {
      int m = c * 16 + l15;
#pragma unroll
      for (int r = 0; r < 4; r++) {
        int trow = t0 + wave * 16 + quad * 4 + r;
        u16 h, l; splitf(d[r], h, l);
        long o = ((long)pair * 512 + trow) * 128 + m;
        qh[o] = h; ql[o] = l;
      }
    } else if (c < 16) {
      int m = (c - 8) * 16 + l15;
#pragma unroll
      for (int r = 0; r < 4; r++) {
        int trow = t0 + wave * 16 + quad * 4 + r;
        u16 h, l; splitf(d[r], h, l);
        long o = ((long)pair * 512 + trow) * 128 + m;
        kh[o] = h; kl[o] = l;
      }
    } else {
      int dcol = (c - 16) * 16 + l15;
#pragma unroll
      for (int r = 0; r < 4; r++) {
        int trow = t0 + wave * 16 + quad * 4 + r;
        u16 h, l; splitf(d[r], h, l);
        long o = ((long)pair * 64 + dcol) * 512 + trow;
        vTh[o] = h; vTl[o] = l;
      }
    }
  }
}

// ---------------- Stage 1b: fused flash kernel (1D grid, pair-XCD swizzle) ----
__global__ __launch_bounds__(256) void k_flash(const u16* qh, const u16* ql,
                                               const u16* kh, const u16* kl,
                                               const u16* vTh, const u16* vTl,
                                               float* rowstats,
                                               u16* ob1h, u16* ob1l, u16* ob2h, u16* ob2l) {
  int bid = blockIdx.x;
  int pair = bid % 120;              // XCD = pair % 8 (120 % 8 == 0); per-pair work uniform
  int t0 = (bid / 120) * 16;
  int tid = threadIdx.x;
  int wave = tid >> 6, lane = tid & 63;
  int l15 = lane & 15, quad = lane >> 4;

  __shared__ float fbig[8704];
  __shared__ float st[2][16][4][4];
  __shared__ float fin[2][16][2];

  const long pb = (long)pair * 512 * 128;
  const u16* qhb = qh + pb; const u16* qlb = ql + pb;
  const u16* khb = kh + pb; const u16* klb = kl + pb;

  float sc[2][8][4];
#pragma unroll
  for (int h = 0; h < 2; h++) {
    long abase = (long)(t0 + l15) * 128 + h * 64 + quad * 8;
    bf16x8 Ah0 = *(const bf16x8*)(qhb + abase);
    bf16x8 Ah1 = *(const bf16x8*)(qhb + abase + 32);
    bf16x8 Al0 = *(const bf16x8*)(qlb + abase);
    bf16x8 Al1 = *(const bf16x8*)(qlb + abase + 32);
#pragma unroll
    for (int ct = 0; ct < 8; ct++) {
      int scol = wave * 128 + ct * 16 + l15;
      long bbase = (long)scol * 128 + h * 64 + quad * 8;
      bf16x8 Bh0 = *(const bf16x8*)(khb + bbase);
      bf16x8 Bh1 = *(const bf16x8*)(khb + bbase + 32);
      bf16x8 Bl0 = *(const bf16x8*)(klb + bbase);
      bf16x8 Bl1 = *(const bf16x8*)(klb + bbase + 32);
      f32x4 d = {0.f, 0.f, 0.f, 0.f};
      d = __builtin_amdgcn_mfma_f32_16x16x32_bf16(Ah0, Bh0, d, 0, 0, 0);
      d = __builtin_amdgcn_mfma_f32_16x16x32_bf16(Ah1, Bh1, d, 0, 0, 0);
      d = __builtin_amdgcn_mfma_f32_16x16x32_bf16(Ah0, Bl0, d, 0, 0, 0);
      d = __builtin_amdgcn_mfma_f32_16x16x32_bf16(Ah1, Bl1, d, 0, 0, 0);
      d = __builtin_amdgcn_mfma_f32_16x16x32_bf16(Al0, Bh0, d, 0, 0, 0);
      d = __builtin_amdgcn_mfma_f32_16x16x32_bf16(Al1, Bh1, d, 0, 0, 0);
#pragma unroll
      for (int r = 0; r < 4; r++) sc[h][ct][r] = d[r] * 0.25f;
    }
  }
#pragma unroll
  for (int h = 0; h < 2; h++)
#pragma unroll
    for (int r = 0; r < 4; r++) {
      float m = -1e30f, mnv = 1e30f;
#pragma unroll
      for (int ct = 0; ct < 8; ct++) { m = fmaxf(m, sc[h][ct][r]); mnv = fminf(mnv, sc[h][ct][r]); }
      for (int d = 1; d < 16; d <<= 1) { m = fmaxf(m, __shfl_xor(m, d)); mnv = fminf(mnv, __shfl_xor(mnv, d)); }
      float z = 0.f, s2 = 0.f;
#pragma unroll
      for (int ct = 0; ct < 8; ct++) { float e = expf(sc[h][ct][r] - m); z += e; s2 += e * e; }
      for (int d = 1; d < 16; d <<= 1) { z += __shfl_xor(z, d); s2 += __shfl_xor(s2, d); }
      if (l15 == 0) {
        st[h][quad * 4 + r][wave][0] = m;  st[h][quad * 4 + r][wave][1] = z;
        st[h][quad * 4 + r][wave][2] = s2; st[h][quad * 4 + r][wave][3] = mnv;
      }
    }
  __syncthreads();
  if (tid < 32) {
    int row = tid & 15, h = tid >> 4;
    float Mf = -1e30f, mnf = 1e30f;
    for (int w = 0; w < 4; w++) { Mf = fmaxf(Mf, st[h][row][w][0]); mnf = fminf(mnf, st[h][row][w][3]); }
    float Z = 0.f, S2 = 0.f;
    for (int w = 0; w < 4; w++) {
      float f = expf(st[h][row][w][0] - Mf);
      Z += st[h][row][w][1] * f; S2 += st[h][row][w][2] * f * f;
    }
    float* o = rowstats + ((long)pair * 512 + t0 + row) * 8 + h * 4;
    o[0] = Mf; o[1] = Z; o[2] = S2; o[3] = mnf;
    fin[h][row][0] = Mf; fin[h][row][1] = 1.0f / Z;
  }
  __syncthreads();
  u16* pbuf = (u16*)fbig;   // [h][wave][row16][136]
#pragma unroll
  for (int h = 0; h < 2; h++)
#pragma unroll
    for (int r = 0; r < 4; r++) {
      int row = quad * 4 + r;
      float Mf = fin[h][row][0], iZ = fin[h][row][1];
#pragma unroll
      for (int ct = 0; ct < 8; ct++) {
        float p = expf(sc[h][ct][r] - Mf) * iZ;
        pbuf[((h * 4 + wave) * 16 + row) * 136 + ct * 16 + l15] = f2b(p);
      }
    }
  __syncthreads();
  f32x4 acc[2][4];
#pragma unroll
  for (int h = 0; h < 2; h++)
#pragma unroll
    for (int nt = 0; nt < 4; nt++) acc[h][nt] = {0.f, 0.f, 0.f, 0.f};
  const u16* vThb = vTh + (long)pair * 64 * 512;
  const u16* vTlb = vTl + (long)pair * 64 * 512;
#pragma unroll
  for (int kc = 0; kc < 4; kc++) {
    int sbase = wave * 128 + kc * 32 + quad * 8;
    bf16x8 A0 = *(const bf16x8*)(pbuf + ((0 * 4 + wave) * 16 + l15) * 136 + kc * 32 + quad * 8);
    bf16x8 A1 = *(const bf16x8*)(pbuf + ((1 * 4 + wave) * 16 + l15) * 136 + kc * 32 + quad * 8);
#pragma unroll
    for (int nt = 0; nt < 4; nt++) {
      long vo = (long)(nt * 16 + l15) * 512 + sbase;
      bf16x8 Vh = *(const bf16x8*)(vThb + vo);
      bf16x8 Vl = *(const bf16x8*)(vTlb + vo);
      acc[0][nt] = __builtin_amdgcn_mfma_f32_16x16x32_bf16(A0, Vh, acc[0][nt], 0, 0, 0);
      acc[0][nt] = __builtin_amdgcn_mfma_f32_16x16x32_bf16(A0, Vl, acc[0][nt], 0, 0, 0);
      acc[1][nt] = __builtin_amdgcn_mfma_f32_16x16x32_bf16(A1, Vh, acc[1][nt], 0, 0, 0);
      acc[1][nt] = __builtin_amdgcn_mfma_f32_16x16x32_bf16(A1, Vl, acc[1][nt], 0, 0, 0);
    }
  }
  __syncthreads();
  float* obr = fbig; // [wave][h][row16][68]
#pragma unroll
  for (int h = 0; h < 2; h++)
#pragma unroll
    for (int nt = 0; nt < 4; nt++)
#pragma unroll
      for (int r = 0; r < 4; r++)
        obr[((wave * 2 + h) * 16 + quad * 4 + r) * 68 + nt * 16 + l15] = acc[h][nt][r];
  __syncthreads();
  for (int i = tid; i < 2048; i += 256) {
    int h = i >> 10, row = (i >> 6) & 15, d = i & 63;
    float s = 0.f;
    for (int w = 0; w < 4; w++) s += obr[((w * 2 + h) * 16 + row) * 68 + d];
    u16 hh, ll; splitf(s, hh, ll);
    long o = ((long)pair * 512 + t0 + row) * 64 + d;
    if (h == 0) { ob1h[o] = hh; ob1l[o] = ll; }
    else        { ob2h[o] = hh; ob2l[o] = ll; }
  }
}

// ---------------- Stage 1c: lambda MLP ----------------
__global__ __launch_bounds__(64) void k_lam(const float* rowstats, fp lw1, fp lb1,
                                            fp lw2, fp lb2, float* lam) {
  int pair = blockIdx.x; int kb = pair >> 2;
  int tid = threadIdx.x;
  const float* rs = rowstats + (long)pair * 512 * 8;
  float mx1 = -1e30f, mn1 = 1e30f, ss1 = 0.f, mx2 = -1e30f, mn2 = 1e30f, ss2 = 0.f;
  for (int j = 0; j < 8; j++) {
    const float* rr = rs + (long)(j * 64 + tid) * 8;
    float M1 = rr[0], Z1 = rr[1], S21 = rr[2], m1 = rr[3];
    float M2 = rr[4], Z2 = rr[5], S22 = rr[6], m2 = rr[7];
    mx1 = fmaxf(mx1, 1.0f / Z1); mn1 = fminf(mn1, expf(m1 - M1) / Z1); ss1 += S21 / (Z1 * Z1);
    mx2 = fmaxf(mx2, 1.0f / Z2); mn2 = fminf(mn2, expf(m2 - M2) / Z2); ss2 += S22 / (Z2 * Z2);
  }
  __shared__ float red[64][8];
  red[tid][0] = mx1; red[tid][1] = mn1; red[tid][2] = ss1;
  red[tid][3] = mx2; red[tid][4] = mn2; red[tid][5] = ss2;
  __syncthreads();
  if (tid == 0) {
    for (int e = 1; e < 64; e++) {
      mx1 = fmaxf(mx1, red[e][0]); mn1 = fminf(mn1, red[e][1]); ss1 += red[e][2];
      mx2 = fmaxf(mx2, red[e][3]); mn2 = fminf(mn2, red[e][4]); ss2 += red[e][5];
    }
    const float mean = 1.0f / 512.0f;
    const float n = 262144.0f;
    float v1 = (ss1 - n * mean * mean) / (n - 1.0f); float sd1 = sqrtf(fmaxf(v1, 0.f));
    float v2 = (ss2 - n * mean * mean) / (n - 1.0f); float sd2 = sqrtf(fmaxf(v2, 0.f));
    float stv[8] = { mean, sd1, mx1, mn1, mean, sd2, mx2, mn2 };
    float acc = lb2[kb];
    for (int o = 0; o < 16; o++) {
      float h = lb1[kb * 16 + o];
      for (int i = 0; i < 8; i++) h += stv[i] * lw1[(kb * 8 + i) * 16 + o];
      h = fmaxf(h, 0.f);
      acc += h * lw2[kb * 16 + o];
    }
    lam[pair] = 1.0f / (1.0f + expf(-acc));
  }
}

// ---------------- Stage 1d: epilogue h1 = ob1@Wo - lam*(ob2@Wo) + bo (MFMA) ---
__global__ __launch_bounds__(256) void k_ep(const u16* ob1h, const u16* ob1l,
                                            const u16* ob2h, const u16* ob2l,
                                            const float* lam, const u16* woh, const u16* wol,
                                            fp bo, u16* h1h, u16* h1l) {
  int pair = blockIdx.y; int kb = pair >> 2, b = pair & 3;
  int t0 = blockIdx.x * 16;
  int tid = threadIdx.x;
  int wave = tid >> 6, lane = tid & 63, l15 = lane & 15, quad = lane >> 4;
  float lv = lam[pair];
  long ab = ((long)pair * 512 + t0 + l15) * 64 + quad * 8;
  bf16x8 A1h[2], A1l[2], A2h[2], A2l[2];
#pragma unroll
  for (int kc = 0; kc < 2; kc++) {
    A1h[kc] = *(const bf16x8*)(ob1h + ab + kc * 32);
    A1l[kc] = *(const bf16x8*)(ob1l + ab + kc * 32);
    A2h[kc] = *(const bf16x8*)(ob2h + ab + kc * 32);
    A2l[kc] = *(const bf16x8*)(ob2l + ab + kc * 32);
  }
  const u16* wbh = woh + (long)kb * 8192;
  const u16* wbl = wol + (long)kb * 8192;
#pragma unroll
  for (int cc = 0; cc < 2; cc++) {
    int c = wave * 2 + cc;
    f32x4 d1 = {0.f, 0.f, 0.f, 0.f}, d2 = {0.f, 0.f, 0.f, 0.f};
#pragma unroll
    for (int kc = 0; kc < 2; kc++) {
      long boff = (long)(c * 16 + l15) * 64 + kc * 32 + quad * 8;
      bf16x8 Bh = *(const bf16x8*)(wbh + boff);
      bf16x8 Bl = *(const bf16x8*)(wbl + boff);
      d1 = __builtin_amdgcn_mfma_f32_16x16x32_bf16(A1h[kc], Bh, d1, 0, 0, 0);
      d1 = __builtin_amdgcn_mfma_f32_16x16x32_bf16(A1h[kc], Bl, d1, 0, 0, 0);
      d1 = __builtin_amdgcn_mfma_f32_16x16x32_bf16(A1l[kc], Bh, d1, 0, 0, 0);
      d2 = __builtin_amdgcn_mfma_f32_16x16x32_bf16(A2h[kc], Bh, d2, 0, 0, 0);
      d2 = __builtin_amdgcn_mfma_f32_16x16x32_bf16(A2h[kc], Bl, d2, 0, 0, 0);
      d2 = __builtin_amdgcn_mfma_f32_16x16x32_bf16(A2l[kc], Bh, d2, 0, 0, 0);
    }
    int n = c * 16 + l15;
    float bias = bo[kb * 128 + n];
#pragma unroll
    for (int r = 0; r < 4; r++) {
      int t = t0 + quad * 4 + r;
      float val = d1[r] - lv * d2[r] + bias;
      u16 h, l; splitf(val, h, l);
      long o = ((long)(b * 30 + kb) * 512 + t) * 128 + n;
      h1h[o] = h; h1l[o] = l;
    }
  }
}

// ---------------- Stage 2a: combined conv kernel, packed active taps ----------
// layout [g 0..455][no 128][ni 128]; g = packed (kb, tap)
__global__ __launch_bounds__(256) void k_ck(fp fw, fp cw2, fp cw4, fp cw8,
                                            fp cw16, fp cw32, u16* ckh, u16* ckl) {
  long idx = (long)blockIdx.x * 256 + threadIdx.x;
  int ni = idx & 127;
  int no = (idx >> 7) & 127;
  int g  = (int)(idx >> 14);
  int kb, r;
  if (g < 192)      { kb = g >> 5;                r = g & 31; }
  else if (g < 336) { int gg = g - 192; kb = 6 + (gg >> 4);  r = 8 + (gg & 15); }
  else              { int gg = g - 336; kb = 15 + (gg >> 3); r = 12 + (gg & 7); }
  float f0 = fw[kb * 3 + 0], f1 = fw[kb * 3 + 1], f2 = fw[kb * 3 + 2];
  float mx = fmaxf(f0, fmaxf(f1, f2));
  float e0 = expf(f0 - mx), e1 = expf(f1 - mx), e2 = expf(f2 - mx);
  float zi = 1.0f / (e0 + e1 + e2);
  float sw[3] = { e0 * zi, e1 * zi, e2 * zi };
  int sbase; fp cws[3];
  if (kb < 6)       { sbase = 8; cws[0] = cw8;  cws[1] = cw16; cws[2] = cw32; }
  else if (kb < 15) { sbase = 4; cws[0] = cw4;  cws[1] = cw8;  cws[2] = cw16; }
  else              { sbase = 2; cws[0] = cw2;  cws[1] = cw4;  cws[2] = cw8;  }
  float val = 0.f;
  int rs = r - 16;
#pragma unroll
  for (int j = 0; j < 3; j++) {
    int s = sbase << j;
    int tau = rs + (s >> 1);
    if (tau >= 0 && tau < s) val += sw[j] * cws[j][((long)no * 128 + ni) * s + tau];
  }
  u16 h, l; splitf(val, h, l);
  ckh[idx] = h; ckl[idx] = l;
}

// ---------------- Stage 2b: per-band conv via MFMA (3D grid, no swizzle) ------
__global__ __launch_bounds__(256) void k_conv(const u16* h1h, const u16* h1l,
                                              const u16* ckh, const u16* ckl, fp fw,
                                              fp cb2, fp cb4, fp cb8, fp cb16,
                                              fp cb32, u16* h2h, u16* h2l) {
  int kb = blockIdx.z, b = blockIdx.y, t0 = blockIdx.x * 64;
  int tid = threadIdx.x;
  int wave = tid >> 6, lane = tid & 63, l15 = lane & 15, quad = lane >> 4;
  __shared__ u16 xs_h[96 * 136];
  __shared__ u16 xs_l[96 * 136];
  const u16* xrh = h1h + (long)(b * 30 + kb) * 512 * 128;
  const u16* xrl = h1l + (long)(b * 30 + kb) * 512 * 128;
  bf16x8 zero8 = {0, 0, 0, 0, 0, 0, 0, 0};
  for (int i = tid; i < 1536; i += 256) {
    int row = i >> 4, c8 = (i & 15) << 3;
    int t = t0 - 16 + row;
    bf16x8 vh = zero8, vl = zero8;
    if (t >= 0 && t < 512) {
      vh = *(const bf16x8*)(xrh + (long)t * 128 + c8);
      vl = *(const bf16x8*)(xrl + (long)t * 128 + c8);
    }
    *(bf16x8*)(xs_h + row * 136 + c8) = vh;
    *(bf16x8*)(xs_l + row * 136 + c8) = vl;
  }
  float f0 = fw[kb * 3 + 0], f1 = fw[kb * 3 + 1], f2 = fw[kb * 3 + 2];
  float mx = fmaxf(f0, fmaxf(f1, f2));
  float e0 = expf(f0 - mx), e1 = expf(f1 - mx), e2 = expf(f2 - mx);
  float zi = 1.0f / (e0 + e1 + e2);
  float sw0 = e0 * zi, sw1 = e1 * zi, sw2 = e2 * zi;
  int rlo, rhi, gbase; fp c0, c1, c2;
  if (kb < 6)       { rlo = 0;  rhi = 32; gbase = kb * 32;             c0 = cb8; c1 = cb16; c2 = cb32; }
  else if (kb < 15) { rlo = 8;  rhi = 24; gbase = 192 + (kb - 6) * 16; c0 = cb4; c1 = cb8;  c2 = cb16; }
  else              { rlo = 12; rhi = 20; gbase = 336 + (kb - 15) * 8; c0 = cb2; c1 = cb4;  c2 = cb8;  }
  __syncthreads();
  f32x4 acc[4][2];
#pragma unroll
  for (int mt = 0; mt < 4; mt++) { acc[mt][0] = {0.f,0.f,0.f,0.f}; acc[mt][1] = {0.f,0.f,0.f,0.f}; }
  for (int r = rlo; r < rhi; r++) {
    const u16* wh = ckh + ((long)(gbase + r - rlo) * 128 + wave * 32 + l15) * 128;
    const u16* wl = ckl + ((long)(gbase + r - rlo) * 128 + wave * 32 + l15) * 128;
#pragma unroll
    for (int c = 0; c < 4; c++) {
      int koff = c * 32 + quad * 8;
      bf16x8 Bh0 = *(const bf16x8*)(wh + koff);
      bf16x8 Bh1 = *(const bf16x8*)(wh + 2048 + koff);
      bf16x8 Bl0 = *(const bf16x8*)(wl + koff);
      bf16x8 Bl1 = *(const bf16x8*)(wl + 2048 + koff);
#pragma unroll
      for (int mt = 0; mt < 4; mt++) {
        int arow = mt * 16 + l15 + r;
        bf16x8 Ah = *(const bf16x8*)(xs_h + arow * 136 + koff);
        bf16x8 Al = *(const bf16x8*)(xs_l + arow * 136 + koff);
        acc[mt][0] = __builtin_amdgcn_mfma_f32_16x16x32_bf16(Ah, Bh0, acc[mt][0], 0, 0, 0);
        acc[mt][0] = __builtin_amdgcn_mfma_f32_16x16x32_bf16(Ah, Bl0, acc[mt][0], 0, 0, 0);
        acc[mt][0] = __builtin_amdgcn_mfma_f32_16x16x32_bf16(Al, Bh0, acc[mt][0], 0, 0, 0);
        acc[mt][1] = __builtin_amdgcn_mfma_f32_16x16x32_bf16(Ah, Bh1, acc[mt][1], 0, 0, 0);
        acc[mt][1] = __builtin_amdgcn_mfma_f32_16x16x32_bf16(Ah, Bl1, acc[mt][1], 0, 0, 0);
        acc[mt][1] = __builtin_amdgcn_mfma_f32_16x16x32_bf16(Al, Bh1, acc[mt][1], 0, 0, 0);
      }
    }
  }
  int no0 = wave * 32 + l15;
  float bias0 = sw0 * c0[no0] + sw1 * c1[no0] + sw2 * c2[no0];
  float bias1 = sw0 * c0[no0 + 16] + sw1 * c1[no0 + 16] + sw2 * c2[no0 + 16];
#pragma unroll
  for (int mt = 0; mt < 4; mt++)
#pragma unroll
    for (int reg = 0; reg < 4; reg++) {
      int t = t0 + mt * 16 + quad * 4 + reg;
      long ob = ((long)(b * 512 + t) * 30 + kb) * 128 + no0;
      u16 h, l;
      splitf(acc[mt][0][reg] + bias0, h, l); h2h[ob] = h;      h2l[ob] = l;
      splitf(acc[mt][1][reg] + bias1, h, l); h2h[ob + 16] = h; h2l[ob + 16] = l;
    }
}

// ---------------- Stage 3: fused graph QKV + attention + out GEMM -------------
__global__ __launch_bounds__(256) void k_gattn(const u16* h2h, const u16* h2l,
                                               const u16* gwh, const u16* gwl,
                                               const float* maskw,
                                               fp gbq, fp gbk, fp gbv, fp gbo,
                                               float* out) {
  int m = blockIdx.x; int b = m >> 9; int t = m & 511;
  int tid = threadIdx.x;
  int wave = tid >> 6, lane = tid & 63, l15 = lane & 15, quad = lane >> 4;
  __shared__ float qs[32][136];
  __shared__ float ks[32][136];
  __shared__ float vs[32][136];
  u16* ogs_h = (u16*)&qs[0][0];
  u16* ogs_l = ogs_h + 32 * 136;

  // ---- Phase 1: QKV projection via MFMA ----
  {
    int mtile = wave & 1;
    int c0 = (wave >> 1) * 12;
    long abase0 = (long)m * 30 * 128;
    bf16x8 Ah[4], Al[4];
    bf16x8 zero8 = {0, 0, 0, 0, 0, 0, 0, 0};
    int row = mtile * 16 + l15;
#pragma unroll
    for (int kc = 0; kc < 4; kc++) {
      if (row < 30) {
        Ah[kc] = *(const bf16x8*)(h2h + abase0 + (long)row * 128 + kc * 32 + quad * 8);
        Al[kc] = *(const bf16x8*)(h2l + abase0 + (long)row * 128 + kc * 32 + quad * 8);
      } else { Ah[kc] = zero8; Al[kc] = zero8; }
    }
    for (int cc = 0; cc < 12; cc++) {
      int c = c0 + cc;
      f32x4 d = {0.f, 0.f, 0.f, 0.f};
#pragma unroll
      for (int kc = 0; kc < 4; kc++) {
        long boff = (long)(c * 16 + l15) * 128 + kc * 32 + quad * 8;
        bf16x8 Bh = *(const bf16x8*)(gwh + boff);
        bf16x8 Bl = *(const bf16x8*)(gwl + boff);
        d = __builtin_amdgcn_mfma_f32_16x16x32_bf16(Ah[kc], Bh, d, 0, 0, 0);
        d = __builtin_amdgcn_mfma_f32_16x16x32_bf16(Ah[kc], Bl, d, 0, 0, 0);
        d = __builtin_amdgcn_mfma_f32_16x16x32_bf16(Al[kc], Bh, d, 0, 0, 0);
      }
      int region = c >> 3;
      int ch = (c & 7) * 16 + l15;
      float bias = (region == 0) ? gbq[ch] : (region == 1) ? gbk[ch] : gbv[ch];
      float (*dst)[136] = (region == 0) ? qs : (region == 1) ? ks : vs;
#pragma unroll
      for (int r = 0; r < 4; r++) {
        int rowo = mtile * 16 + quad * 4 + r;
        if (rowo < 30) dst[rowo][ch] = d[r] + bias;
      }
    }
  }
  __syncthreads();

  // ---- Phase 2: 30x30 4-head attention (VALU) ----
  float p[30]; float iZ = 0.f; int hi = 0, ii = 0;
  if (tid < 120) {
    hi = tid / 30; ii = tid % 30;
    int hb = hi * 32;
    float4 qv[8];
#pragma unroll
    for (int dq = 0; dq < 8; dq++) qv[dq] = *(const float4*)&qs[ii][hb + dq * 4];
    float mx = -1e30f;
#pragma unroll
    for (int j = 0; j < 30; j++) {
      float s = 0.f;
      const float4* kr = (const float4*)&ks[j][hb];
#pragma unroll
      for (int dq = 0; dq < 8; dq++) {
        float4 kv = kr[dq];
        s += qv[dq].x * kv.x + qv[dq].y * kv.y + qv[dq].z * kv.z + qv[dq].w * kv.w;
      }
      s *= 0.17677669529663687f;
      p[j] = (maskw[ii * 30 + j] != 0.f) ? s : -1e30f;
      mx = fmaxf(mx, p[j]);
    }
    float Z = 0.f;
#pragma unroll
    for (int j = 0; j < 30; j++) { float e = expf(p[j] - mx); p[j] = e; Z += e; }
    iZ = 1.0f / Z;
  }
  __syncthreads();
  if (tid < 120) {
    int hb = hi * 32;
#pragma unroll
    for (int dq = 0; dq < 8; dq++) {
      float sx = 0.f, sy = 0.f, sz = 0.f, sw2 = 0.f;
#pragma unroll
      for (int j = 0; j < 30; j++) {
        float4 vv = *(const float4*)&vs[j][hb + dq * 4];
        sx += p[j] * vv.x; sy += p[j] * vv.y; sz += p[j] * vv.z; sw2 += p[j] * vv.w;
      }
      float o4[4] = { sx * iZ, sy * iZ, sz * iZ, sw2 * iZ };
#pragma unroll
      for (int cpt = 0; cpt < 4; cpt++) {
        u16 h, l; splitf(o4[cpt], h, l);
        ogs_h[ii * 136 + hb + dq * 4 + cpt] = h;
        ogs_l[ii * 136 + hb + dq * 4 + cpt] = l;
      }
    }
  }
  __syncthreads();

  // ---- Phase 3: out = og @ gWo + gbo via MFMA ----
  {
    int mtile = wave & 1;
    int nc0 = (wave >> 1) * 4;
    int row = mtile * 16 + l15;
    bf16x8 Ah[4], Al[4];
#pragma unroll
    for (int kc = 0; kc < 4; kc++) {
      Ah[kc] = *(const bf16x8*)(ogs_h + row * 136 + kc * 32 + quad * 8);
      Al[kc] = *(const bf16x8*)(ogs_l + row * 136 + kc * 32 + quad * 8);
    }
    for (int cc = 0; cc < 4; cc++) {
      int nchunk = nc0 + cc;
      f32x4 d = {0.f, 0.f, 0.f, 0.f};
#pragma unroll
      for (int kc = 0; kc < 4; kc++) {
        long boff = (long)(384 + nchunk * 16 + l15) * 128 + kc * 32 + quad * 8;
        bf16x8 Bh = *(const bf16x8*)(gwh + boff);
        bf16x8 Bl = *(const bf16x8*)(gwl + boff);
        d = __builtin_amdgcn_mfma_f32_16x16x32_bf16(Ah[kc], Bh, d, 0, 0, 0);
        d = __builtin_amdgcn_mfma_f32_16x16x32_bf16(Ah[kc], Bl, d, 0, 0, 0);
        d = __builtin_amdgcn_mfma_f32_16x16x32_bf16(Al[kc], Bh, d, 0, 0, 0);
      }
      int n = nchunk * 16 + l15;
      float gb = gbo[n];
      long obase = ((long)(b * 128 + n) * 512 + t) * 30;
#pragma unroll
      for (int r = 0; r < 4; r++) {
        int kbo = mtile * 16 + quad * 4 + r;
        if (kbo < 30) out[obase + kbo] = d[r] + gb;
      }
    }
  }
}

extern "C" void kernel_launch(void* const* d_in, const int* in_sizes, int n_in,
                              void* d_out, int out_size, void* d_ws, size_t ws_size,
                              hipStream_t stream) {
  fp x = (fp)d_in[0], Wq = (fp)d_in[1], Wk = (fp)d_in[2], Wv = (fp)d_in[3],
     Wo = (fp)d_in[4], bo = (fp)d_in[5], lw1 = (fp)d_in[6], lb1 = (fp)d_in[7],
     lw2 = (fp)d_in[8], lb2 = (fp)d_in[9],
     cw2 = (fp)d_in[10], cb2 = (fp)d_in[11], cw4 = (fp)d_in[12], cb4 = (fp)d_in[13],
     cw8 = (fp)d_in[14], cb8 = (fp)d_in[15], cw16 = (fp)d_in[16], cb16 = (fp)d_in[17],
     cw32 = (fp)d_in[18], cb32 = (fp)d_in[19], fw = (fp)d_in[20], be = (fp)d_in[21],
     gWq = (fp)d_in[22], gbq = (fp)d_in[23], gWk = (fp)d_in[24], gbk = (fp)d_in[25],
     gWv = (fp)d_in[26], gbv = (fp)d_in[27], gWo = (fp)d_in[28], gbo = (fp)d_in[29];
  (void)in_sizes; (void)n_in; (void)out_size; (void)ws_size;

  float* ws = (float*)d_ws;
  // ---- workspace map (float offsets), race-free stage-ordered aliasing ----
  u16* qh  = (u16*)ws;                          // [120][512][128]
  u16* ql  = (u16*)(ws + 3932160L);
  u16* kh  = (u16*)(ws + 7864320L);
  u16* kl  = (u16*)(ws + 11796480L);
  u16* vTh = (u16*)(ws + 15728640L);            // [120][64][512]
  u16* vTl = (u16*)(ws + 17694720L);
  float* rowstats = ws + 19660800L;             // [120][512][8]
  float* lam      = ws + 20152320L;             // [120]
  u16* wqkT_h = (u16*)(ws + 20152448L);         // [30][320][128]
  u16* wqkT_l = (u16*)(ws + 20766848L);
  u16* gwT_h  = (u16*)(ws + 21381248L);         // [512][128]
  u16* gwT_l  = (u16*)(ws + 21414016L);
  float* maskw = ws + 21446784L;                // [900]
  u16* woT_h = (u16*)(ws + 21447808L);          // [30][128][64]
  u16* woT_l = (u16*)(ws + 21570688L);
  u16* ob1h = (u16*)(ws + 21693568L);           // [120][512][64] each
  u16* ob1l = (u16*)(ws + 23659648L);
  u16* ob2h = (u16*)(ws + 25625728L);
  u16* ob2l = (u16*)(ws + 27591808L);           // ends 29,557,888 (118.2 MB peak)
  u16* h1h = (u16*)ws;                          // over dead qh/ql (after k_flash)
  u16* h1l = (u16*)(ws + 3932160L);
  u16* h2h = (u16*)(ws + 7864320L);             // over dead kh/kl
  u16* h2l = (u16*)(ws + 11796480L);
  u16* ckh = (u16*)(ws + 21693568L);            // over dead ob* (after k_ep)
  u16* ckl = (u16*)(ws + 25429120L);

  k_adj<<<1, 64, 0, stream>>>(be, maskw);
  k_wt_band<<<dim3(30, 4), 256, 0, stream>>>(Wq, Wk, Wv, Wo, wqkT_h, wqkT_l, woT_h, woT_l);
  k_wt_graph<<<4, 256, 0, stream>>>(gWq, gWk, gWv, gWo, gwT_h, gwT_l);
  k_qkv<<<dim3(8, 4, 30), 256, 0, stream>>>(x, wqkT_h, wqkT_l, qh, ql, kh, kl, vTh, vTl);
  k_flash<<<3840, 256, 0, stream>>>(qh, ql, kh, kl, vTh, vTl, rowstats, ob1h, ob1l, ob2h, ob2l);
  k_lam<<<120, 64, 0, stream>>>(rowstats, lw1, lb1, lw2, lb2, lam);
  k_ep<<<dim3(32, 120), 256, 0, stream>>>(ob1h, ob1l, ob2h, ob2l, lam, woT_h, woT_l, bo, h1h, h1l);
  k_ck<<<29184, 256, 0, stream>>>(fw, cw2, cw4, cw8, cw16, cw32, ckh, ckl);
  k_conv<<<dim3(8, 4, 30), 256, 0, stream>>>(h1h, h1l, ckh, ckl, fw, cb2, cb4, cb8, cb16, cb32, h2h, h2l);
  k_gattn<<<2048, 256, 0, stream>>>(h2h, h2l, gwT_h, gwT_l, maskw, gbq, gbk, gbv, gbo, (float*)d_out);
}

// Round 8
// 857.272 us; speedup vs baseline: 1.2884x; 1.0233x over previous
//
#include <hip/hip_runtime.h>

// Problem constants: B=4, N=128, T=512, K=30 bands. All I/O fp32.
typedef const float* fp;
typedef unsigned short u16;
typedef __attribute__((ext_vector_type(8))) short bf16x8;   // 8 bf16 = 4 VGPRs
typedef __attribute__((ext_vector_type(4))) float f32x4;

__device__ __forceinline__ u16 f2b(float f) {
  union { float f; unsigned u; } a; a.f = f;
  unsigned u = a.u;
  u += 0x7fffu + ((u >> 16) & 1u);   // RNE
  return (u16)(u >> 16);
}
// split fp32 into hi (truncated bf16) + lo (RNE bf16 of exact remainder)
__device__ __forceinline__ void splitf(float x, u16& h, u16& l) {
  union { float f; unsigned u; } a; a.f = x;
  unsigned hu = a.u & 0xFFFF0000u;
  h = (u16)(hu >> 16);
  union { unsigned u; float f; } b; b.u = hu;
  l = f2b(x - b.f);
}

// ---------------- Stage 0: adjacency mask ----------------
__global__ __launch_bounds__(64) void k_adj(fp be, float* mask) {
  __shared__ float e[30][65];
  __shared__ float sim[30][33];
  __shared__ float A[30][33];
  int tid = threadIdx.x;
  for (int idx = tid; idx < 30 * 64; idx += 64) e[idx / 64][idx % 64] = be[idx];
  __syncthreads();
  if (tid < 30) {
    float s = 0.f;
    for (int d = 0; d < 64; d++) s += e[tid][d] * e[tid][d];
    float sc = 1.0f / (sqrtf(s) + 1e-8f);
    for (int d = 0; d < 64; d++) e[tid][d] *= sc;
  }
  __syncthreads();
  if (tid < 30) {
    for (int j = 0; j < 30; j++) {
      float s = 0.f;
      for (int d = 0; d < 64; d++) s += e[tid][d] * e[j][d];
      sim[tid][j] = s;
    }
    for (int j = 0; j < 30; j++) A[tid][j] = 0.f;
  }
  __syncthreads();
  if (tid < 30) {
    unsigned used = 0;
    for (int t = 0; t < 5; t++) {
      float best = -1e30f; int bi = 0;
      for (int j = 0; j < 30; j++)
        if (!((used >> j) & 1u) && sim[tid][j] > best) { best = sim[tid][j]; bi = j; }
      A[tid][bi] = best; used |= 1u << bi;
    }
  }
  __syncthreads();
  for (int idx = tid; idx < 900; idx += 64) {
    int i = idx / 30, j = idx % 30;
    float s = A[i][j] + A[j][i];
    mask[idx] = (s != 0.0f) ? 1.0f : 0.0f;
  }
}

// ---------------- Prep: transpose+split band weights into B-frag layout -------
// which 0..2 -> wqkT[kb][m 0..319][n]; which 3 -> woT[kb][n 0..127][d 0..63]
__global__ __launch_bounds__(256) void k_wt_band(fp Wq, fp Wk, fp Wv, fp Wo,
                                                 u16* wh, u16* wl, u16* woh, u16* wol) {
  int kb = blockIdx.x, which = blockIdx.y;
  __shared__ float wsb[128][129];
  int tid = threadIdx.x;
  if (which == 3) {
    fp src = Wo + kb * 8192;          // [64][128]
    for (int i = tid; i < 8192; i += 256) {
      int d = i >> 7, n = i & 127;
      wsb[n][d] = src[i];
    }
    __syncthreads();
    long base = (long)kb * 8192;
    for (int o = tid; o < 8192; o += 256) {
      u16 h, l; splitf(wsb[o >> 6][o & 63], h, l);
      woh[base + o] = h; wol[base + o] = l;
    }
    return;
  }
  int M = (which == 2) ? 64 : 128;
  int sh = (which == 2) ? 6 : 7;
  fp src = (which == 0) ? (Wq + kb * 16384) : (which == 1) ? (Wk + kb * 16384) : (Wv + kb * 8192);
  for (int i = tid; i < 128 * M; i += 256) {
    int n = i >> sh, m = i & (M - 1);
    wsb[n][m] = src[i];
  }
  __syncthreads();
  long base = (long)kb * 40960 + which * 16384;
  for (int o = tid; o < 128 * M; o += 256) {
    int m = o >> 7, n = o & 127;
    u16 h, l; splitf(wsb[n][m], h, l);
    wh[base + m * 128 + n] = h; wl[base + m * 128 + n] = l;
  }
}

// gwT[m 0..511][n]: gWq 0..127, gWk 128..255, gWv 256..383, gWo 384..511
__global__ __launch_bounds__(256) void k_wt_graph(fp gWq, fp gWk, fp gWv, fp gWo,
                                                  u16* wh, u16* wl) {
  int w = blockIdx.x;
  fp src = (w == 0) ? gWq : (w == 1) ? gWk : (w == 2) ? gWv : gWo;
  __shared__ float wsb[128][129];
  int tid = threadIdx.x;
  for (int i = tid; i < 16384; i += 256) wsb[i >> 7][i & 127] = src[i];
  __syncthreads();
  long base = (long)w * 16384;
  for (int o = tid; o < 16384; o += 256) {
    int m = o >> 7, n = o & 127;
    u16 h, l; splitf(wsb[n][m], h, l);
    wh[base + m * 128 + n] = h; wl[base + m * 128 + n] = l;
  }
}

// ---------------- Stage 1a: QKV projections via MFMA ----------------
// 1D grid: bid = kb*32 + (b*8+ts)  ->  XCD = (b*8+ts)%8; all 30 bands of one
// (b,t0) x-tile share an XCD's L2 (x lines are reused across bands).
__global__ __launch_bounds__(256) void k_qkv(fp x, const u16* wh, const u16* wl,
                                             u16* qh, u16* ql, u16* kh, u16* kl,
                                             u16* vTh, u16* vTl) {
  int bid = blockIdx.x;
  int kb = bid >> 5;
  int rem = bid & 31;
  int b = rem >> 3, t0 = (rem & 7) * 64;
  int tid = threadIdx.x;
  int wave = tid >> 6, lane = tid & 63, l15 = lane & 15, quad = lane >> 4;
  __shared__ u16 xs_h[64 * 136];
  __shared__ u16 xs_l[64 * 136];
  for (int i = tid; i < 8192; i += 256) {
    int tl = i >> 7, n = i & 127;
    float v = x[((long)(b * 128 + n) * 512 + t0 + tl) * 30 + kb];
    u16 h, l; splitf(v, h, l);
    xs_h[tl * 136 + n] = h; xs_l[tl * 136 + n] = l;
  }
  __syncthreads();
  int arow = wave * 16 + l15;
  bf16x8 Ah[4], Al[4];
#pragma unroll
  for (int kc = 0; kc < 4; kc++) {
    Ah[kc] = *(const bf16x8*)(xs_h + arow * 136 + kc * 32 + quad * 8);
    Al[kc] = *(const bf16x8*)(xs_l + arow * 136 + kc * 32 + quad * 8);
  }
  int pair = kb * 4 + b;
  const u16* wbh = wh + (long)kb * 40960;
  const u16* wbl = wl + (long)kb * 40960;
  for (int c = 0; c < 20; c++) {
    f32x4 d = {0.f, 0.f, 0.f, 0.f};
#pragma unroll
    for (int kc = 0; kc < 4; kc++) {
      long boff = (long)(c * 16 + l15) * 128 + kc * 32 + quad * 8;
      bf16x8 Bh = *(const bf16x8*)(wbh + boff);
      bf16x8 Bl = *(const bf16x8*)(wbl + boff);
      d = __builtin_amdgcn_mfma_f32_16x16x32_bf16(Ah[kc], Bh, d, 0, 0, 0);
      d = __builtin_amdgcn_mfma_f32_16x16x32_bf16(Ah[kc], Bl, d, 0, 0, 0);
      d = __builtin_amdgcn_mfma_f32_16x16x32_bf16(Al[kc], Bh, d, 0, 0, 0);
    }
    if (c < 8) {
      int m = c * 16 + l15;
#pragma unroll
      for (int r = 0; r < 4; r++) {
        int trow = t0 + wave * 16 + quad * 4 + r;
        u16 h, l; splitf(d[r], h, l);
        long o = ((long)pair * 512 + trow) * 128 + m;
        qh[o] = h; ql[o] = l;
      }
    } else if (c < 16) {
      int m = (c - 8) * 16 + l15;
#pragma unroll
      for (int r = 0; r < 4; r++) {
        int trow = t0 + wave * 16 + quad * 4 + r;
        u16 h, l; splitf(d[r], h, l);
        long o = ((long)pair * 512 + trow) * 128 + m;
        kh[o] = h; kl[o] = l;
      }
    } else {
      int dcol = (c - 16) * 16 + l15;
      ushort4 vh4, vl4;
      u16 h, l;
      splitf(d[0], h, l); vh4.x = h; vl4.x = l;
      splitf(d[1], h, l); vh4.y = h; vl4.y = l;
      splitf(d[2], h, l); vh4.z = h; vl4.z = l;
      splitf(d[3], h, l); vh4.w = h; vl4.w = l;
      int trow0 = t0 + wave * 16 + quad * 4;
      long o = ((long)pair * 64 + dcol) * 512 + trow0;
      *(ushort4*)(vTh + o) = vh4;
      *(ushort4*)(vTl + o) = vl4;
    }
  }
}

// ---------------- Stage 1b: fused flash kernel (1D grid, pair-XCD swizzle) ----
__global__ __launch_bounds__(256) void k_flash(const u16* qh, const u16* ql,
                                               const u16* kh, const u16* kl,
                                               const u16* vTh, const u16* vTl,
                                               float* rowstats,
                                               u16* ob1h, u16* ob1l, u16* ob2h, u16* ob2l) {
  int bid = blockIdx.x;
  int pair = bid % 120;              // XCD = pair % 8 (120 % 8 == 0); per-pair work uniform
  int t0 = (bid / 120) * 16;
  int tid = threadIdx.x;
  int wave = tid >> 6, lane = tid & 63;
  int l15 = lane & 15, quad = lane >> 4;

  __shared__ float fbig[8704];
  __shared__ float st[2][16][4][4];
  __shared__ float fin[2][16][2];

  const long pb = (long)pair * 512 * 128;
  const u16* qhb = qh + pb; const u16* qlb = ql + pb;
  const u16* khb = kh + pb; const u16* klb = kl + pb;

  float sc[2][8][4];
#pragma unroll
  for (int h = 0; h < 2; h++) {
    long abase = (long)(t0 + l15) * 128 + h * 64 + quad * 8;
    bf16x8 Ah0 = *(const bf16x8*)(qhb + abase);
    bf16x8 Ah1 = *(const bf16x8*)(qhb + abase + 32);
    bf16x8 Al0 = *(const bf16x8*)(qlb + abase);
    bf16x8 Al1 = *(const bf16x8*)(qlb + abase + 32);
#pragma unroll
    for (int ct = 0; ct < 8; ct++) {
      int scol = wave * 128 + ct * 16 + l15;
      long bbase = (long)scol * 128 + h * 64 + quad * 8;
      bf16x8 Bh0 = *(const bf16x8*)(khb + bbase);
      bf16x8 Bh1 = *(const bf16x8*)(khb + bbase + 32);
      bf16x8 Bl0 = *(const bf16x8*)(klb + bbase);
      bf16x8 Bl1 = *(const bf16x8*)(klb + bbase + 32);
      f32x4 d = {0.f, 0.f, 0.f, 0.f};
      d = __builtin_amdgcn_mfma_f32_16x16x32_bf16(Ah0, Bh0, d, 0, 0, 0);
      d = __builtin_amdgcn_mfma_f32_16x16x32_bf16(Ah1, Bh1, d, 0, 0, 0);
      d = __builtin_amdgcn_mfma_f32_16x16x32_bf16(Ah0, Bl0, d, 0, 0, 0);
      d = __builtin_amdgcn_mfma_f32_16x16x32_bf16(Ah1, Bl1, d, 0, 0, 0);
      d = __builtin_amdgcn_mfma_f32_16x16x32_bf16(Al0, Bh0, d, 0, 0, 0);
      d = __builtin_amdgcn_mfma_f32_16x16x32_bf16(Al1, Bh1, d, 0, 0, 0);
#pragma unroll
      for (int r = 0; r < 4; r++) sc[h][ct][r] = d[r] * 0.25f;
    }
  }
#pragma unroll
  for (int h = 0; h < 2; h++)
#pragma unroll
    for (int r = 0; r < 4; r++) {
      float m = -1e30f, mnv = 1e30f;
#pragma unroll
      for (int ct = 0; ct < 8; ct++) { m = fmaxf(m, sc[h][ct][r]); mnv = fminf(mnv, sc[h][ct][r]); }
      for (int d = 1; d < 16; d <<= 1) { m = fmaxf(m, __shfl_xor(m, d)); mnv = fminf(mnv, __shfl_xor(mnv, d)); }
      float z = 0.f, s2 = 0.f;
#pragma unroll
      for (int ct = 0; ct < 8; ct++) { float e = __expf(sc[h][ct][r] - m); z += e; s2 += e * e; }
      for (int d = 1; d < 16; d <<= 1) { z += __shfl_xor(z, d); s2 += __shfl_xor(s2, d); }
      if (l15 == 0) {
        st[h][quad * 4 + r][wave][0] = m;  st[h][quad * 4 + r][wave][1] = z;
        st[h][quad * 4 + r][wave][2] = s2; st[h][quad * 4 + r][wave][3] = mnv;
      }
    }
  __syncthreads();
  if (tid < 32) {
    int row = tid & 15, h = tid >> 4;
    float Mf = -1e30f, mnf = 1e30f;
    for (int w = 0; w < 4; w++) { Mf = fmaxf(Mf, st[h][row][w][0]); mnf = fminf(mnf, st[h][row][w][3]); }
    float Z = 0.f, S2 = 0.f;
    for (int w = 0; w < 4; w++) {
      float f = __expf(st[h][row][w][0] - Mf);
      Z += st[h][row][w][1] * f; S2 += st[h][row][w][2] * f * f;
    }
    float* o = rowstats + ((long)pair * 512 + t0 + row) * 8 + h * 4;
    o[0] = Mf; o[1] = Z; o[2] = S2; o[3] = mnf;
    fin[h][row][0] = Mf; fin[h][row][1] = 1.0f / Z;
  }
  __syncthreads();
  u16* pbuf = (u16*)fbig;   // [h][wave][row16][136]
#pragma unroll
  for (int h = 0; h < 2; h++)
#pragma unroll
    for (int r = 0; r < 4; r++) {
      int row = quad * 4 + r;
      float Mf = fin[h][row][0], iZ = fin[h][row][1];
#pragma unroll
      for (int ct = 0; ct < 8; ct++) {
        float p = __expf(sc[h][ct][r] - Mf) * iZ;
        pbuf[((h * 4 + wave) * 16 + row) * 136 + ct * 16 + l15] = f2b(p);
      }
    }
  __syncthreads();
  f32x4 acc[2][4];
#pragma unroll
  for (int h = 0; h < 2; h++)
#pragma unroll
    for (int nt = 0; nt < 4; nt++) acc[h][nt] = {0.f, 0.f, 0.f, 0.f};
  const u16* vThb = vTh + (long)pair * 64 * 512;
  const u16* vTlb = vTl + (long)pair * 64 * 512;
#pragma unroll
  for (int kc = 0; kc < 4; kc++) {
    int sbase = wave * 128 + kc * 32 + quad * 8;
    bf16x8 A0 = *(const bf16x8*)(pbuf + ((0 * 4 + wave) * 16 + l15) * 136 + kc * 32 + quad * 8);
    bf16x8 A1 = *(const bf16x8*)(pbuf + ((1 * 4 + wave) * 16 + l15) * 136 + kc * 32 + quad * 8);
#pragma unroll
    for (int nt = 0; nt < 4; nt++) {
      long vo = (long)(nt * 16 + l15) * 512 + sbase;
      bf16x8 Vh = *(const bf16x8*)(vThb + vo);
      bf16x8 Vl = *(const bf16x8*)(vTlb + vo);
      acc[0][nt] = __builtin_amdgcn_mfma_f32_16x16x32_bf16(A0, Vh, acc[0][nt], 0, 0, 0);
      acc[0][nt] = __builtin_amdgcn_mfma_f32_16x16x32_bf16(A0, Vl, acc[0][nt], 0, 0, 0);
      acc[1][nt] = __builtin_amdgcn_mfma_f32_16x16x32_bf16(A1, Vh, acc[1][nt], 0, 0, 0);
      acc[1][nt] = __builtin_amdgcn_mfma_f32_16x16x32_bf16(A1, Vl, acc[1][nt], 0, 0, 0);
    }
  }
  __syncthreads();
  float* obr = fbig; // [wave][h][row16][68]
#pragma unroll
  for (int h = 0; h < 2; h++)
#pragma unroll
    for (int nt = 0; nt < 4; nt++)
#pragma unroll
      for (int r = 0; r < 4; r++)
        obr[((wave * 2 + h) * 16 + quad * 4 + r) * 68 + nt * 16 + l15] = acc[h][nt][r];
  __syncthreads();
  for (int i = tid; i < 2048; i += 256) {
    int h = i >> 10, row = (i >> 6) & 15, d = i & 63;
    float s = 0.f;
    for (int w = 0; w < 4; w++) s += obr[((w * 2 + h) * 16 + row) * 68 + d];
    u16 hh, ll; splitf(s, hh, ll);
    long o = ((long)pair * 512 + t0 + row) * 64 + d;
    if (h == 0) { ob1h[o] = hh; ob1l[o] = ll; }
    else        { ob2h[o] = hh; ob2l[o] = ll; }
  }
}

// ---------------- Stage 1c: lambda MLP ----------------
__global__ __launch_bounds__(64) void k_lam(const float* rowstats, fp lw1, fp lb1,
                                            fp lw2, fp lb2, float* lam) {
  int pair = blockIdx.x; int kb = pair >> 2;
  int tid = threadIdx.x;
  const float* rs = rowstats + (long)pair * 512 * 8;
  float mx1 = -1e30f, mn1 = 1e30f, ss1 = 0.f, mx2 = -1e30f, mn2 = 1e30f, ss2 = 0.f;
  for (int j = 0; j < 8; j++) {
    const float* rr = rs + (long)(j * 64 + tid) * 8;
    float M1 = rr[0], Z1 = rr[1], S21 = rr[2], m1 = rr[3];
    float M2 = rr[4], Z2 = rr[5], S22 = rr[6], m2 = rr[7];
    mx1 = fmaxf(mx1, 1.0f / Z1); mn1 = fminf(mn1, __expf(m1 - M1) / Z1); ss1 += S21 / (Z1 * Z1);
    mx2 = fmaxf(mx2, 1.0f / Z2); mn2 = fminf(mn2, __expf(m2 - M2) / Z2); ss2 += S22 / (Z2 * Z2);
  }
  __shared__ float red[64][8];
  red[tid][0] = mx1; red[tid][1] = mn1; red[tid][2] = ss1;
  red[tid][3] = mx2; red[tid][4] = mn2; red[tid][5] = ss2;
  __syncthreads();
  if (tid == 0) {
    for (int e = 1; e < 64; e++) {
      mx1 = fmaxf(mx1, red[e][0]); mn1 = fminf(mn1, red[e][1]); ss1 += red[e][2];
      mx2 = fmaxf(mx2, red[e][3]); mn2 = fminf(mn2, red[e][4]); ss2 += red[e][5];
    }
    const float mean = 1.0f / 512.0f;
    const float n = 262144.0f;
    float v1 = (ss1 - n * mean * mean) / (n - 1.0f); float sd1 = sqrtf(fmaxf(v1, 0.f));
    float v2 = (ss2 - n * mean * mean) / (n - 1.0f); float sd2 = sqrtf(fmaxf(v2, 0.f));
    float stv[8] = { mean, sd1, mx1, mn1, mean, sd2, mx2, mn2 };
    float acc = lb2[kb];
    for (int o = 0; o < 16; o++) {
      float h = lb1[kb * 16 + o];
      for (int i = 0; i < 8; i++) h += stv[i] * lw1[(kb * 8 + i) * 16 + o];
      h = fmaxf(h, 0.f);
      acc += h * lw2[kb * 16 + o];
    }
    lam[pair] = 1.0f / (1.0f + __expf(-acc));
  }
}

// ---------------- Stage 1d: epilogue h1 = ob1@Wo - lam*(ob2@Wo) + bo (MFMA) ---
__global__ __launch_bounds__(256) void k_ep(const u16* ob1h, const u16* ob1l,
                                            const u16* ob2h, const u16* ob2l,
                                            const float* lam, const u16* woh, const u16* wol,
                                            fp bo, u16* h1h, u16* h1l) {
  int pair = blockIdx.y; int kb = pair >> 2, b = pair & 3;
  int t0 = blockIdx.x * 16;
  int tid = threadIdx.x;
  int wave = tid >> 6, lane = tid & 63, l15 = lane & 15, quad = lane >> 4;
  float lv = lam[pair];
  long ab = ((long)pair * 512 + t0 + l15) * 64 + quad * 8;
  bf16x8 A1h[2], A1l[2], A2h[2], A2l[2];
#pragma unroll
  for (int kc = 0; kc < 2; kc++) {
    A1h[kc] = *(const bf16x8*)(ob1h + ab + kc * 32);
    A1l[kc] = *(const bf16x8*)(ob1l + ab + kc * 32);
    A2h[kc] = *(const bf16x8*)(ob2h + ab + kc * 32);
    A2l[kc] = *(const bf16x8*)(ob2l + ab + kc * 32);
  }
  const u16* wbh = woh + (long)kb * 8192;
  const u16* wbl = wol + (long)kb * 8192;
#pragma unroll
  for (int cc = 0; cc < 2; cc++) {
    int c = wave * 2 + cc;
    f32x4 d1 = {0.f, 0.f, 0.f, 0.f}, d2 = {0.f, 0.f, 0.f, 0.f};
#pragma unroll
    for (int kc = 0; kc < 2; kc++) {
      long boff = (long)(c * 16 + l15) * 64 + kc * 32 + quad * 8;
      bf16x8 Bh = *(const bf16x8*)(wbh + boff);
      bf16x8 Bl = *(const bf16x8*)(wbl + boff);
      d1 = __builtin_amdgcn_mfma_f32_16x16x32_bf16(A1h[kc], Bh, d1, 0, 0, 0);
      d1 = __builtin_amdgcn_mfma_f32_16x16x32_bf16(A1h[kc], Bl, d1, 0, 0, 0);
      d1 = __builtin_amdgcn_mfma_f32_16x16x32_bf16(A1l[kc], Bh, d1, 0, 0, 0);
      d2 = __builtin_amdgcn_mfma_f32_16x16x32_bf16(A2h[kc], Bh, d2, 0, 0, 0);
      d2 = __builtin_amdgcn_mfma_f32_16x16x32_bf16(A2h[kc], Bl, d2, 0, 0, 0);
      d2 = __builtin_amdgcn_mfma_f32_16x16x32_bf16(A2l[kc], Bh, d2, 0, 0, 0);
    }
    int n = c * 16 + l15;
    float bias = bo[kb * 128 + n];
#pragma unroll
    for (int r = 0; r < 4; r++) {
      int t = t0 + quad * 4 + r;
      float val = d1[r] - lv * d2[r] + bias;
      u16 h, l; splitf(val, h, l);
      long o = ((long)(b * 30 + kb) * 512 + t) * 128 + n;
      h1h[o] = h; h1l[o] = l;
    }
  }
}

// ---------------- Stage 2a: combined conv kernel, packed active taps ----------
// layout [g 0..455][no 128][ni 128]; g = packed (kb, tap)
__global__ __launch_bounds__(256) void k_ck(fp fw, fp cw2, fp cw4, fp cw8,
                                            fp cw16, fp cw32, u16* ckh, u16* ckl) {
  long idx = (long)blockIdx.x * 256 + threadIdx.x;
  int ni = idx & 127;
  int no = (idx >> 7) & 127;
  int g  = (int)(idx >> 14);
  int kb, r;
  if (g < 192)      { kb = g >> 5;                r = g & 31; }
  else if (g < 336) { int gg = g - 192; kb = 6 + (gg >> 4);  r = 8 + (gg & 15); }
  else              { int gg = g - 336; kb = 15 + (gg >> 3); r = 12 + (gg & 7); }
  float f0 = fw[kb * 3 + 0], f1 = fw[kb * 3 + 1], f2 = fw[kb * 3 + 2];
  float mx = fmaxf(f0, fmaxf(f1, f2));
  float e0 = __expf(f0 - mx), e1 = __expf(f1 - mx), e2 = __expf(f2 - mx);
  float zi = 1.0f / (e0 + e1 + e2);
  float sw[3] = { e0 * zi, e1 * zi, e2 * zi };
  int sbase; fp cws[3];
  if (kb < 6)       { sbase = 8; cws[0] = cw8;  cws[1] = cw16; cws[2] = cw32; }
  else if (kb < 15) { sbase = 4; cws[0] = cw4;  cws[1] = cw8;  cws[2] = cw16; }
  else              { sbase = 2; cws[0] = cw2;  cws[1] = cw4;  cws[2] = cw8;  }
  float val = 0.f;
  int rs = r - 16;
#pragma unroll
  for (int j = 0; j < 3; j++) {
    int s = sbase << j;
    int tau = rs + (s >> 1);
    if (tau >= 0 && tau < s) val += sw[j] * cws[j][((long)no * 128 + ni) * s + tau];
  }
  u16 h, l; splitf(val, h, l);
  ckh[idx] = h; ckl[idx] = l;
}

// ---------------- Stage 2b: per-band conv via MFMA (3D grid, no swizzle) ------
__global__ __launch_bounds__(256) void k_conv(const u16* h1h, const u16* h1l,
                                              const u16* ckh, const u16* ckl, fp fw,
                                              fp cb2, fp cb4, fp cb8, fp cb16,
                                              fp cb32, u16* h2h, u16* h2l) {
  int kb = blockIdx.z, b = blockIdx.y, t0 = blockIdx.x * 64;
  int tid = threadIdx.x;
  int wave = tid >> 6, lane = tid & 63, l15 = lane & 15, quad = lane >> 4;
  __shared__ u16 xs_h[96 * 136];
  __shared__ u16 xs_l[96 * 136];
  const u16* xrh = h1h + (long)(b * 30 + kb) * 512 * 128;
  const u16* xrl = h1l + (long)(b * 30 + kb) * 512 * 128;
  bf16x8 zero8 = {0, 0, 0, 0, 0, 0, 0, 0};
  for (int i = tid; i < 1536; i += 256) {
    int row = i >> 4, c8 = (i & 15) << 3;
    int t = t0 - 16 + row;
    bf16x8 vh = zero8, vl = zero8;
    if (t >= 0 && t < 512) {
      vh = *(const bf16x8*)(xrh + (long)t * 128 + c8);
      vl = *(const bf16x8*)(xrl + (long)t * 128 + c8);
    }
    *(bf16x8*)(xs_h + row * 136 + c8) = vh;
    *(bf16x8*)(xs_l + row * 136 + c8) = vl;
  }
  float f0 = fw[kb * 3 + 0], f1 = fw[kb * 3 + 1], f2 = fw[kb * 3 + 2];
  float mx = fmaxf(f0, fmaxf(f1, f2));
  float e0 = __expf(f0 - mx), e1 = __expf(f1 - mx), e2 = __expf(f2 - mx);
  float zi = 1.0f / (e0 + e1 + e2);
  float sw0 = e0 * zi, sw1 = e1 * zi, sw2 = e2 * zi;
  int rlo, rhi, gbase; fp c0, c1, c2;
  if (kb < 6)       { rlo = 0;  rhi = 32; gbase = kb * 32;             c0 = cb8; c1 = cb16; c2 = cb32; }
  else if (kb < 15) { rlo = 8;  rhi = 24; gbase = 192 + (kb - 6) * 16; c0 = cb4; c1 = cb8;  c2 = cb16; }
  else              { rlo = 12; rhi = 20; gbase = 336 + (kb - 15) * 8; c0 = cb2; c1 = cb4;  c2 = cb8;  }
  __syncthreads();
  f32x4 acc[4][2];
#pragma unroll
  for (int mt = 0; mt < 4; mt++) { acc[mt][0] = {0.f,0.f,0.f,0.f}; acc[mt][1] = {0.f,0.f,0.f,0.f}; }
  for (int r = rlo; r < rhi; r++) {
    const u16* wh = ckh + ((long)(gbase + r - rlo) * 128 + wave * 32 + l15) * 128;
    const u16* wl = ckl + ((long)(gbase + r - rlo) * 128 + wave * 32 + l15) * 128;
#pragma unroll
    for (int c = 0; c < 4; c++) {
      int koff = c * 32 + quad * 8;
      bf16x8 Bh0 = *(const bf16x8*)(wh + koff);
      bf16x8 Bh1 = *(const bf16x8*)(wh + 2048 + koff);
      bf16x8 Bl0 = *(const bf16x8*)(wl + koff);
      bf16x8 Bl1 = *(const bf16x8*)(wl + 2048 + koff);
#pragma unroll
      for (int mt = 0; mt < 4; mt++) {
        int arow = mt * 16 + l15 + r;
        bf16x8 Ah = *(const bf16x8*)(xs_h + arow * 136 + koff);
        bf16x8 Al = *(const bf16x8*)(xs_l + arow * 136 + koff);
        acc[mt][0] = __builtin_amdgcn_mfma_f32_16x16x32_bf16(Ah, Bh0, acc[mt][0], 0, 0, 0);
        acc[mt][0] = __builtin_amdgcn_mfma_f32_16x16x32_bf16(Ah, Bl0, acc[mt][0], 0, 0, 0);
        acc[mt][0] = __builtin_amdgcn_mfma_f32_16x16x32_bf16(Al, Bh0, acc[mt][0], 0, 0, 0);
        acc[mt][1] = __builtin_amdgcn_mfma_f32_16x16x32_bf16(Ah, Bh1, acc[mt][1], 0, 0, 0);
        acc[mt][1] = __builtin_amdgcn_mfma_f32_16x16x32_bf16(Ah, Bl1, acc[mt][1], 0, 0, 0);
        acc[mt][1] = __builtin_amdgcn_mfma_f32_16x16x32_bf16(Al, Bh1, acc[mt][1], 0, 0, 0);
      }
    }
  }
  int no0 = wave * 32 + l15;
  float bias0 = sw0 * c0[no0] + sw1 * c1[no0] + sw2 * c2[no0];
  float bias1 = sw0 * c0[no0 + 16] + sw1 * c1[no0 + 16] + sw2 * c2[no0 + 16];
#pragma unroll
  for (int mt = 0; mt < 4; mt++)
#pragma unroll
    for (int reg = 0; reg < 4; reg++) {
      int t = t0 + mt * 16 + quad * 4 + reg;
      long ob = ((long)(b * 512 + t) * 30 + kb) * 128 + no0;
      u16 h, l;
      splitf(acc[mt][0][reg] + bias0, h, l); h2h[ob] = h;      h2l[ob] = l;
      splitf(acc[mt][1][reg] + bias1, h, l); h2h[ob + 16] = h; h2l[ob + 16] = l;
    }
}

// ---------------- Stage 3: fused graph QKV + attention + out GEMM -------------
__global__ __launch_bounds__(256) void k_gattn(const u16* h2h, const u16* h2l,
                                               const u16* gwh, const u16* gwl,
                                               const float* maskw,
                                               fp gbq, fp gbk, fp gbv, fp gbo,
                                               float* out) {
  int m = blockIdx.x; int b = m >> 9; int t = m & 511;
  int tid = threadIdx.x;
  int wave = tid >> 6, lane = tid & 63, l15 = lane & 15, quad = lane >> 4;
  __shared__ float qs[32][136];
  __shared__ float ks[32][136];
  __shared__ float vs[32][136];
  u16* ogs_h = (u16*)&qs[0][0];
  u16* ogs_l = ogs_h + 32 * 136;

  // ---- Phase 1: QKV projection via MFMA ----
  {
    int mtile = wave & 1;
    int c0 = (wave >> 1) * 12;
    long abase0 = (long)m * 30 * 128;
    bf16x8 Ah[4], Al[4];
    bf16x8 zero8 = {0, 0, 0, 0, 0, 0, 0, 0};
    int row = mtile * 16 + l15;
#pragma unroll
    for (int kc = 0; kc < 4; kc++) {
      if (row < 30) {
        Ah[kc] = *(const bf16x8*)(h2h + abase0 + (long)row * 128 + kc * 32 + quad * 8);
        Al[kc] = *(const bf16x8*)(h2l + abase0 + (long)row * 128 + kc * 32 + quad * 8);
      } else { Ah[kc] = zero8; Al[kc] = zero8; }
    }
    for (int cc = 0; cc < 12; cc++) {
      int c = c0 + cc;
      f32x4 d = {0.f, 0.f, 0.f, 0.f};
#pragma unroll
      for (int kc = 0; kc < 4; kc++) {
        long boff = (long)(c * 16 + l15) * 128 + kc * 32 + quad * 8;
        bf16x8 Bh = *(const bf16x8*)(gwh + boff);
        bf16x8 Bl = *(const bf16x8*)(gwl + boff);
        d = __builtin_amdgcn_mfma_f32_16x16x32_bf16(Ah[kc], Bh, d, 0, 0, 0);
        d = __builtin_amdgcn_mfma_f32_16x16x32_bf16(Ah[kc], Bl, d, 0, 0, 0);
        d = __builtin_amdgcn_mfma_f32_16x16x32_bf16(Al[kc], Bh, d, 0, 0, 0);
      }
      int region = c >> 3;
      int ch = (c & 7) * 16 + l15;
      float bias = (region == 0) ? gbq[ch] : (region == 1) ? gbk[ch] : gbv[ch];
      float (*dst)[136] = (region == 0) ? qs : (region == 1) ? ks : vs;
#pragma unroll
      for (int r = 0; r < 4; r++) {
        int rowo = mtile * 16 + quad * 4 + r;
        if (rowo < 30) dst[rowo][ch] = d[r] + bias;
      }
    }
  }
  __syncthreads();

  // ---- Phase 2: 30x30 4-head attention (VALU) ----
  float p[30]; float iZ = 0.f; int hi = 0, ii = 0;
  if (tid < 120) {
    hi = tid / 30; ii = tid % 30;
    int hb = hi * 32;
    float4 qv[8];
#pragma unroll
    for (int dq = 0; dq < 8; dq++) qv[dq] = *(const float4*)&qs[ii][hb + dq * 4];
    float mx = -1e30f;
#pragma unroll
    for (int j = 0; j < 30; j++) {
      float s = 0.f;
      const float4* kr = (const float4*)&ks[j][hb];
#pragma unroll
      for (int dq = 0; dq < 8; dq++) {
        float4 kv = kr[dq];
        s += qv[dq].x * kv.x + qv[dq].y * kv.y + qv[dq].z * kv.z + qv[dq].w * kv.w;
      }
      s *= 0.17677669529663687f;
      p[j] = (maskw[ii * 30 + j] != 0.f) ? s : -1e30f;
      mx = fmaxf(mx, p[j]);
    }
    float Z = 0.f;
#pragma unroll
    for (int j = 0; j < 30; j++) { float e = __expf(p[j] - mx); p[j] = e; Z += e; }
    iZ = 1.0f / Z;
  }
  __syncthreads();
  if (tid < 120) {
    int hb = hi * 32;
#pragma unroll
    for (int dq = 0; dq < 8; dq++) {
      float sx = 0.f, sy = 0.f, sz = 0.f, sw2 = 0.f;
#pragma unroll
      for (int j = 0; j < 30; j++) {
        float4 vv = *(const float4*)&vs[j][hb + dq * 4];
        sx += p[j] * vv.x; sy += p[j] * vv.y; sz += p[j] * vv.z; sw2 += p[j] * vv.w;
      }
      float o4[4] = { sx * iZ, sy * iZ, sz * iZ, sw2 * iZ };
#pragma unroll
      for (int cpt = 0; cpt < 4; cpt++) {
        u16 h, l; splitf(o4[cpt], h, l);
        ogs_h[ii * 136 + hb + dq * 4 + cpt] = h;
        ogs_l[ii * 136 + hb + dq * 4 + cpt] = l;
      }
    }
  }
  __syncthreads();

  // ---- Phase 3: out = og @ gWo + gbo via MFMA ----
  {
    int mtile = wave & 1;
    int nc0 = (wave >> 1) * 4;
    int row = mtile * 16 + l15;
    bf16x8 Ah[4], Al[4];
#pragma unroll
    for (int kc = 0; kc < 4; kc++) {
      Ah[kc] = *(const bf16x8*)(ogs_h + row * 136 + kc * 32 + quad * 8);
      Al[kc] = *(const bf16x8*)(ogs_l + row * 136 + kc * 32 + quad * 8);
    }
    for (int cc = 0; cc < 4; cc++) {
      int nchunk = nc0 + cc;
      f32x4 d = {0.f, 0.f, 0.f, 0.f};
#pragma unroll
      for (int kc = 0; kc < 4; kc++) {
        long boff = (long)(384 + nchunk * 16 + l15) * 128 + kc * 32 + quad * 8;
        bf16x8 Bh = *(const bf16x8*)(gwh + boff);
        bf16x8 Bl = *(const bf16x8*)(gwl + boff);
        d = __builtin_amdgcn_mfma_f32_16x16x32_bf16(Ah[kc], Bh, d, 0, 0, 0);
        d = __builtin_amdgcn_mfma_f32_16x16x32_bf16(Ah[kc], Bl, d, 0, 0, 0);
        d = __builtin_amdgcn_mfma_f32_16x16x32_bf16(Al[kc], Bh, d, 0, 0, 0);
      }
      int n = nchunk * 16 + l15;
      float gb = gbo[n];
      long obase = ((long)(b * 128 + n) * 512 + t) * 30;
#pragma unroll
      for (int r = 0; r < 4; r++) {
        int kbo = mtile * 16 + quad * 4 + r;
        if (kbo < 30) out[obase + kbo] = d[r] + gb;
      }
    }
  }
}

extern "C" void kernel_launch(void* const* d_in, const int* in_sizes, int n_in,
                              void* d_out, int out_size, void* d_ws, size_t ws_size,
                              hipStream_t stream) {
  fp x = (fp)d_in[0], Wq = (fp)d_in[1], Wk = (fp)d_in[2], Wv = (fp)d_in[3],
     Wo = (fp)d_in[4], bo = (fp)d_in[5], lw1 = (fp)d_in[6], lb1 = (fp)d_in[7],
     lw2 = (fp)d_in[8], lb2 = (fp)d_in[9],
     cw2 = (fp)d_in[10], cb2 = (fp)d_in[11], cw4 = (fp)d_in[12], cb4 = (fp)d_in[13],
     cw8 = (fp)d_in[14], cb8 = (fp)d_in[15], cw16 = (fp)d_in[16], cb16 = (fp)d_in[17],
     cw32 = (fp)d_in[18], cb32 = (fp)d_in[19], fw = (fp)d_in[20], be = (fp)d_in[21],
     gWq = (fp)d_in[22], gbq = (fp)d_in[23], gWk = (fp)d_in[24], gbk = (fp)d_in[25],
     gWv = (fp)d_in[26], gbv = (fp)d_in[27], gWo = (fp)d_in[28], gbo = (fp)d_in[29];
  (void)in_sizes; (void)n_in; (void)out_size; (void)ws_size;

  float* ws = (float*)d_ws;
  // ---- workspace map (float offsets), race-free stage-ordered aliasing ----
  u16* qh  = (u16*)ws;                          // [120][512][128]
  u16* ql  = (u16*)(ws + 3932160L);
  u16* kh  = (u16*)(ws + 7864320L);
  u16* kl  = (u16*)(ws + 11796480L);
  u16* vTh = (u16*)(ws + 15728640L);            // [120][64][512]
  u16* vTl = (u16*)(ws + 17694720L);
  float* rowstats = ws + 19660800L;             // [120][512][8]
  float* lam      = ws + 20152320L;             // [120]
  u16* wqkT_h = (u16*)(ws + 20152448L);         // [30][320][128]
  u16* wqkT_l = (u16*)(ws + 20766848L);
  u16* gwT_h  = (u16*)(ws + 21381248L);         // [512][128]
  u16* gwT_l  = (u16*)(ws + 21414016L);
  float* maskw = ws + 21446784L;                // [900]
  u16* woT_h = (u16*)(ws + 21447808L);          // [30][128][64]
  u16* woT_l = (u16*)(ws + 21570688L);
  u16* ob1h = (u16*)(ws + 21693568L);           // [120][512][64] each
  u16* ob1l = (u16*)(ws + 23659648L);
  u16* ob2h = (u16*)(ws + 25625728L);
  u16* ob2l = (u16*)(ws + 27591808L);           // ends 29,557,888 (118.2 MB peak)
  u16* h1h = (u16*)ws;                          // over dead qh/ql (after k_flash)
  u16* h1l = (u16*)(ws + 3932160L);
  u16* h2h = (u16*)(ws + 7864320L);             // over dead kh/kl
  u16* h2l = (u16*)(ws + 11796480L);
  u16* ckh = (u16*)(ws + 21693568L);            // over dead ob* (after k_ep)
  u16* ckl = (u16*)(ws + 25429120L);

  k_adj<<<1, 64, 0, stream>>>(be, maskw);
  k_wt_band<<<dim3(30, 4), 256, 0, stream>>>(Wq, Wk, Wv, Wo, wqkT_h, wqkT_l, woT_h, woT_l);
  k_wt_graph<<<4, 256, 0, stream>>>(gWq, gWk, gWv, gWo, gwT_h, gwT_l);
  k_qkv<<<960, 256, 0, stream>>>(x, wqkT_h, wqkT_l, qh, ql, kh, kl, vTh, vTl);
  k_flash<<<3840, 256, 0, stream>>>(qh, ql, kh, kl, vTh, vTl, rowstats, ob1h, ob1l, ob2h, ob2l);
  k_lam<<<120, 64, 0, stream>>>(rowstats, lw1, lb1, lw2, lb2, lam);
  k_ep<<<dim3(32, 120), 256, 0, stream>>>(ob1h, ob1l, ob2h, ob2l, lam, woT_h, woT_l, bo, h1h, h1l);
  k_ck<<<29184, 256, 0, stream>>>(fw, cw2, cw4, cw8, cw16, cw32, ckh, ckl);
  k_conv<<<dim3(8, 4, 30), 256, 0, stream>>>(h1h, h1l, ckh, ckl, fw, cb2, cb4, cb8, cb16, cb32, h2h, h2l);
  k_gattn<<<2048, 256, 0, stream>>>(h2h, h2l, gwT_h, gwT_l, maskw, gbq, gbk, gbv, gbo, (float*)d_out);
}

// Round 10
// 851.589 us; speedup vs baseline: 1.2970x; 1.0067x over previous
//
#include <hip/hip_runtime.h>

// Problem constants: B=4, N=128, T=512, K=30 bands. All I/O fp32.
typedef const float* fp;
typedef unsigned short u16;
typedef __attribute__((ext_vector_type(8))) short bf16x8;   // 8 bf16 = 4 VGPRs
typedef __attribute__((ext_vector_type(4))) float f32x4;

__device__ __forceinline__ u16 f2b(float f) {
  union { float f; unsigned u; } a; a.f = f;
  unsigned u = a.u;
  u += 0x7fffu + ((u >> 16) & 1u);   // RNE
  return (u16)(u >> 16);
}
// split fp32 into hi (truncated bf16) + lo (RNE bf16 of exact remainder)
__device__ __forceinline__ void splitf(float x, u16& h, u16& l) {
  union { float f; unsigned u; } a; a.f = x;
  unsigned hu = a.u & 0xFFFF0000u;
  h = (u16)(hu >> 16);
  union { unsigned u; float f; } b; b.u = hu;
  l = f2b(x - b.f);
}

// ---------------- Stage 0: adjacency mask ----------------
__global__ __launch_bounds__(64) void k_adj(fp be, float* mask) {
  __shared__ float e[30][65];
  __shared__ float sim[30][33];
  __shared__ float A[30][33];
  int tid = threadIdx.x;
  for (int idx = tid; idx < 30 * 64; idx += 64) e[idx / 64][idx % 64] = be[idx];
  __syncthreads();
  if (tid < 30) {
    float s = 0.f;
    for (int d = 0; d < 64; d++) s += e[tid][d] * e[tid][d];
    float sc = 1.0f / (sqrtf(s) + 1e-8f);
    for (int d = 0; d < 64; d++) e[tid][d] *= sc;
  }
  __syncthreads();
  if (tid < 30) {
    for (int j = 0; j < 30; j++) {
      float s = 0.f;
      for (int d = 0; d < 64; d++) s += e[tid][d] * e[j][d];
      sim[tid][j] = s;
    }
    for (int j = 0; j < 30; j++) A[tid][j] = 0.f;
  }
  __syncthreads();
  if (tid < 30) {
    unsigned used = 0;
    for (int t = 0; t < 5; t++) {
      float best = -1e30f; int bi = 0;
      for (int j = 0; j < 30; j++)
        if (!((used >> j) & 1u) && sim[tid][j] > best) { best = sim[tid][j]; bi = j; }
      A[tid][bi] = best; used |= 1u << bi;
    }
  }
  __syncthreads();
  for (int idx = tid; idx < 900; idx += 64) {
    int i = idx / 30, j = idx % 30;
    float s = A[i][j] + A[j][i];
    mask[idx] = (s != 0.0f) ? 1.0f : 0.0f;
  }
}

// ---------------- Prep: transpose+split band weights into B-frag layout -------
// which 0..2 -> wqkT[kb][m 0..319][n]; which 3 -> woT[kb][n 0..127][d 0..63]
__global__ __launch_bounds__(256) void k_wt_band(fp Wq, fp Wk, fp Wv, fp Wo,
                                                 u16* wh, u16* wl, u16* woh, u16* wol) {
  int kb = blockIdx.x, which = blockIdx.y;
  __shared__ float wsb[128][129];
  int tid = threadIdx.x;
  if (which == 3) {
    fp src = Wo + kb * 8192;          // [64][128]
    for (int i = tid; i < 8192; i += 256) {
      int d = i >> 7, n = i & 127;
      wsb[n][d] = src[i];
    }
    __syncthreads();
    long base = (long)kb * 8192;
    for (int o = tid; o < 8192; o += 256) {
      u16 h, l; splitf(wsb[o >> 6][o & 63], h, l);
      woh[base + o] = h; wol[base + o] = l;
    }
    return;
  }
  int M = (which == 2) ? 64 : 128;
  int sh = (which == 2) ? 6 : 7;
  fp src = (which == 0) ? (Wq + kb * 16384) : (which == 1) ? (Wk + kb * 16384) : (Wv + kb * 8192);
  for (int i = tid; i < 128 * M; i += 256) {
    int n = i >> sh, m = i & (M - 1);
    wsb[n][m] = src[i];
  }
  __syncthreads();
  long base = (long)kb * 40960 + which * 16384;
  for (int o = tid; o < 128 * M; o += 256) {
    int m = o >> 7, n = o & 127;
    u16 h, l; splitf(wsb[n][m], h, l);
    wh[base + m * 128 + n] = h; wl[base + m * 128 + n] = l;
  }
}

// gwT[m 0..511][n]: gWq 0..127, gWk 128..255, gWv 256..383, gWo 384..511
__global__ __launch_bounds__(256) void k_wt_graph(fp gWq, fp gWk, fp gWv, fp gWo,
                                                  u16* wh, u16* wl) {
  int w = blockIdx.x;
  fp src = (w == 0) ? gWq : (w == 1) ? gWk : (w == 2) ? gWv : gWo;
  __shared__ float wsb[128][129];
  int tid = threadIdx.x;
  for (int i = tid; i < 16384; i += 256) wsb[i >> 7][i & 127] = src[i];
  __syncthreads();
  long base = (long)w * 16384;
  for (int o = tid; o < 16384; o += 256) {
    int m = o >> 7, n = o & 127;
    u16 h, l; splitf(wsb[n][m], h, l);
    wh[base + m * 128 + n] = h; wl[base + m * 128 + n] = l;
  }
}

// ---------------- Stage 1a: QKV projections via MFMA ----------------
// 1D grid: bid = kb*32 + (b*8+ts)  ->  XCD = (b*8+ts)%8; all 30 bands of one
// (b,t0) x-tile share an XCD's L2 (x lines are reused across bands).
__global__ __launch_bounds__(256) void k_qkv(fp x, const u16* wh, const u16* wl,
                                             u16* qh, u16* ql, u16* kh, u16* kl,
                                             u16* vTh, u16* vTl) {
  int bid = blockIdx.x;
  int kb = bid >> 5;
  int rem = bid & 31;
  int b = rem >> 3, t0 = (rem & 7) * 64;
  int tid = threadIdx.x;
  int wave = tid >> 6, lane = tid & 63, l15 = lane & 15, quad = lane >> 4;
  __shared__ u16 xs_h[64 * 136];
  __shared__ u16 xs_l[64 * 136];
  for (int i = tid; i < 8192; i += 256) {
    int tl = i >> 7, n = i & 127;
    float v = x[((long)(b * 128 + n) * 512 + t0 + tl) * 30 + kb];
    u16 h, l; splitf(v, h, l);
    xs_h[tl * 136 + n] = h; xs_l[tl * 136 + n] = l;
  }
  __syncthreads();
  int arow = wave * 16 + l15;
  bf16x8 Ah[4], Al[4];
#pragma unroll
  for (int kc = 0; kc < 4; kc++) {
    Ah[kc] = *(const bf16x8*)(xs_h + arow * 136 + kc * 32 + quad * 8);
    Al[kc] = *(const bf16x8*)(xs_l + arow * 136 + kc * 32 + quad * 8);
  }
  int pair = kb * 4 + b;
  const u16* wbh = wh + (long)kb * 40960;
  const u16* wbl = wl + (long)kb * 40960;
  for (int c = 0; c < 20; c++) {
    f32x4 d = {0.f, 0.f, 0.f, 0.f};
#pragma unroll
    for (int kc = 0; kc < 4; kc++) {
      long boff = (long)(c * 16 + l15) * 128 + kc * 32 + quad * 8;
      bf16x8 Bh = *(const bf16x8*)(wbh + boff);
      bf16x8 Bl = *(const bf16x8*)(wbl + boff);
      d = __builtin_amdgcn_mfma_f32_16x16x32_bf16(Ah[kc], Bh, d, 0, 0, 0);
      d = __builtin_amdgcn_mfma_f32_16x16x32_bf16(Ah[kc], Bl, d, 0, 0, 0);
      d = __builtin_amdgcn_mfma_f32_16x16x32_bf16(Al[kc], Bh, d, 0, 0, 0);
    }
    if (c < 8) {
      int m = c * 16 + l15;
#pragma unroll
      for (int r = 0; r < 4; r++) {
        int trow = t0 + wave * 16 + quad * 4 + r;
        u16 h, l; splitf(d[r], h, l);
        long o = ((long)pair * 512 + trow) * 128 + m;
        qh[o] = h; ql[o] = l;
      }
    } else if (c < 16) {
      int m = (c - 8) * 16 + l15;
#pragma unroll
      for (int r = 0; r < 4; r++) {
        int trow = t0 + wave * 16 + quad * 4 + r;
        u16 h, l; splitf(d[r], h, l);
        long o = ((long)pair * 512 + trow) * 128 + m;
        kh[o] = h; kl[o] = l;
      }
    } else {
      int dcol = (c - 16) * 16 + l15;
      ushort4 vh4, vl4;
      u16 h, l;
      splitf(d[0], h, l); vh4.x = h; vl4.x = l;
      splitf(d[1], h, l); vh4.y = h; vl4.y = l;
      splitf(d[2], h, l); vh4.z = h; vl4.z = l;
      splitf(d[3], h, l); vh4.w = h; vl4.w = l;
      int trow0 = t0 + wave * 16 + quad * 4;
      long o = ((long)pair * 64 + dcol) * 512 + trow0;
      *(ushort4*)(vTh + o) = vh4;
      *(ushort4*)(vTl + o) = vl4;
    }
  }
}

// ---------------- Stage 1b: fused flash kernel (round-8 version, known good) --
__global__ __launch_bounds__(256) void k_flash(const u16* qh, const u16* ql,
                                               const u16* kh, const u16* kl,
                                               const u16* vTh, const u16* vTl,
                                               float* rowstats,
                                               u16* ob1h, u16* ob1l, u16* ob2h, u16* ob2l) {
  int bid = blockIdx.x;
  int pair = bid % 120;              // XCD = pair % 8 (120 % 8 == 0)
  int t0 = (bid / 120) * 16;
  int tid = threadIdx.x;
  int wave = tid >> 6, lane = tid & 63;
  int l15 = lane & 15, quad = lane >> 4;

  __shared__ float fbig[8704];
  __shared__ float st[2][16][4][4];
  __shared__ float fin[2][16][2];

  const long pb = (long)pair * 512 * 128;
  const u16* qhb = qh + pb; const u16* qlb = ql + pb;
  const u16* khb = kh + pb; const u16* klb = kl + pb;

  float sc[2][8][4];
#pragma unroll
  for (int h = 0; h < 2; h++) {
    long abase = (long)(t0 + l15) * 128 + h * 64 + quad * 8;
    bf16x8 Ah0 = *(const bf16x8*)(qhb + abase);
    bf16x8 Ah1 = *(const bf16x8*)(qhb + abase + 32);
    bf16x8 Al0 = *(const bf16x8*)(qlb + abase);
    bf16x8 Al1 = *(const bf16x8*)(qlb + abase + 32);
#pragma unroll
    for (int ct = 0; ct < 8; ct++) {
      int scol = wave * 128 + ct * 16 + l15;
      long bbase = (long)scol * 128 + h * 64 + quad * 8;
      bf16x8 Bh0 = *(const bf16x8*)(khb + bbase);
      bf16x8 Bh1 = *(const bf16x8*)(khb + bbase + 32);
      bf16x8 Bl0 = *(const bf16x8*)(klb + bbase);
      bf16x8 Bl1 = *(const bf16x8*)(klb + bbase + 32);
      f32x4 d = {0.f, 0.f, 0.f, 0.f};
      d = __builtin_amdgcn_mfma_f32_16x16x32_bf16(Ah0, Bh0, d, 0, 0, 0);
      d = __builtin_amdgcn_mfma_f32_16x16x32_bf16(Ah1, Bh1, d, 0, 0, 0);
      d = __builtin_amdgcn_mfma_f32_16x16x32_bf16(Ah0, Bl0, d, 0, 0, 0);
      d = __builtin_amdgcn_mfma_f32_16x16x32_bf16(Ah1, Bl1, d, 0, 0, 0);
      d = __builtin_amdgcn_mfma_f32_16x16x32_bf16(Al0, Bh0, d, 0, 0, 0);
      d = __builtin_amdgcn_mfma_f32_16x16x32_bf16(Al1, Bh1, d, 0, 0, 0);
#pragma unroll
      for (int r = 0; r < 4; r++) sc[h][ct][r] = d[r] * 0.25f;
    }
  }
#pragma unroll
  for (int h = 0; h < 2; h++)
#pragma unroll
    for (int r = 0; r < 4; r++) {
      float m = -1e30f, mnv = 1e30f;
#pragma unroll
      for (int ct = 0; ct < 8; ct++) { m = fmaxf(m, sc[h][ct][r]); mnv = fminf(mnv, sc[h][ct][r]); }
      for (int d = 1; d < 16; d <<= 1) { m = fmaxf(m, __shfl_xor(m, d)); mnv = fminf(mnv, __shfl_xor(mnv, d)); }
      float z = 0.f, s2 = 0.f;
#pragma unroll
      for (int ct = 0; ct < 8; ct++) { float e = __expf(sc[h][ct][r] - m); z += e; s2 += e * e; }
      for (int d = 1; d < 16; d <<= 1) { z += __shfl_xor(z, d); s2 += __shfl_xor(s2, d); }
      if (l15 == 0) {
        st[h][quad * 4 + r][wave][0] = m;  st[h][quad * 4 + r][wave][1] = z;
        st[h][quad * 4 + r][wave][2] = s2; st[h][quad * 4 + r][wave][3] = mnv;
      }
    }
  __syncthreads();
  if (tid < 32) {
    int row = tid & 15, h = tid >> 4;
    float Mf = -1e30f, mnf = 1e30f;
    for (int w = 0; w < 4; w++) { Mf = fmaxf(Mf, st[h][row][w][0]); mnf = fminf(mnf, st[h][row][w][3]); }
    float Z = 0.f, S2 = 0.f;
    for (int w = 0; w < 4; w++) {
      float f = __expf(st[h][row][w][0] - Mf);
      Z += st[h][row][w][1] * f; S2 += st[h][row][w][2] * f * f;
    }
    float* o = rowstats + ((long)pair * 512 + t0 + row) * 8 + h * 4;
    o[0] = Mf; o[1] = Z; o[2] = S2; o[3] = mnf;
    fin[h][row][0] = Mf; fin[h][row][1] = 1.0f / Z;
  }
  __syncthreads();
  u16* pbuf = (u16*)fbig;   // [h][wave][row16][136]
#pragma unroll
  for (int h = 0; h < 2; h++)
#pragma unroll
    for (int r = 0; r < 4; r++) {
      int row = quad * 4 + r;
      float Mf = fin[h][row][0], iZ = fin[h][row][1];
#pragma unroll
      for (int ct = 0; ct < 8; ct++) {
        float p = __expf(sc[h][ct][r] - Mf) * iZ;
        pbuf[((h * 4 + wave) * 16 + row) * 136 + ct * 16 + l15] = f2b(p);
      }
    }
  __syncthreads();
  f32x4 acc[2][4];
#pragma unroll
  for (int h = 0; h < 2; h++)
#pragma unroll
    for (int nt = 0; nt < 4; nt++) acc[h][nt] = {0.f, 0.f, 0.f, 0.f};
  const u16* vThb = vTh + (long)pair * 64 * 512;
  const u16* vTlb = vTl + (long)pair * 64 * 512;
#pragma unroll
  for (int kc = 0; kc < 4; kc++) {
    int sbase = wave * 128 + kc * 32 + quad * 8;
    bf16x8 A0 = *(const bf16x8*)(pbuf + ((0 * 4 + wave) * 16 + l15) * 136 + kc * 32 + quad * 8);
    bf16x8 A1 = *(const bf16x8*)(pbuf + ((1 * 4 + wave) * 16 + l15) * 136 + kc * 32 + quad * 8);
#pragma unroll
    for (int nt = 0; nt < 4; nt++) {
      long vo = (long)(nt * 16 + l15) * 512 + sbase;
      bf16x8 Vh = *(const bf16x8*)(vThb + vo);
      bf16x8 Vl = *(const bf16x8*)(vTlb + vo);
      acc[0][nt] = __builtin_amdgcn_mfma_f32_16x16x32_bf16(A0, Vh, acc[0][nt], 0, 0, 0);
      acc[0][nt] = __builtin_amdgcn_mfma_f32_16x16x32_bf16(A0, Vl, acc[0][nt], 0, 0, 0);
      acc[1][nt] = __builtin_amdgcn_mfma_f32_16x16x32_bf16(A1, Vh, acc[1][nt], 0, 0, 0);
      acc[1][nt] = __builtin_amdgcn_mfma_f32_16x16x32_bf16(A1, Vl, acc[1][nt], 0, 0, 0);
    }
  }
  __syncthreads();
  float* obr = fbig; // [wave][h][row16][68]
#pragma unroll
  for (int h = 0; h < 2; h++)
#pragma unroll
    for (int nt = 0; nt < 4; nt++)
#pragma unroll
      for (int r = 0; r < 4; r++)
        obr[((wave * 2 + h) * 16 + quad * 4 + r) * 68 + nt * 16 + l15] = acc[h][nt][r];
  __syncthreads();
  for (int i = tid; i < 2048; i += 256) {
    int h = i >> 10, row = (i >> 6) & 15, d = i & 63;
    float s = 0.f;
    for (int w = 0; w < 4; w++) s += obr[((w * 2 + h) * 16 + row) * 68 + d];
    u16 hh, ll; splitf(s, hh, ll);
    long o = ((long)pair * 512 + t0 + row) * 64 + d;
    if (h == 0) { ob1h[o] = hh; ob1l[o] = ll; }
    else        { ob2h[o] = hh; ob2l[o] = ll; }
  }
}

// ---------------- Stage 1c: lambda MLP ----------------
__global__ __launch_bounds__(64) void k_lam(const float* rowstats, fp lw1, fp lb1,
                                            fp lw2, fp lb2, float* lam) {
  int pair = blockIdx.x; int kb = pair >> 2;
  int tid = threadIdx.x;
  const float* rs = rowstats + (long)pair * 512 * 8;
  float mx1 = -1e30f, mn1 = 1e30f, ss1 = 0.f, mx2 = -1e30f, mn2 = 1e30f, ss2 = 0.f;
  for (int j = 0; j < 8; j++) {
    const float* rr = rs + (long)(j * 64 + tid) * 8;
    float M1 = rr[0], Z1 = rr[1], S21 = rr[2], m1 = rr[3];
    float M2 = rr[4], Z2 = rr[5], S22 = rr[6], m2 = rr[7];
    mx1 = fmaxf(mx1, 1.0f / Z1); mn1 = fminf(mn1, __expf(m1 - M1) / Z1); ss1 += S21 / (Z1 * Z1);
    mx2 = fmaxf(mx2, 1.0f / Z2); mn2 = fminf(mn2, __expf(m2 - M2) / Z2); ss2 += S22 / (Z2 * Z2);
  }
  __shared__ float red[64][8];
  red[tid][0] = mx1; red[tid][1] = mn1; red[tid][2] = ss1;
  red[tid][3] = mx2; red[tid][4] = mn2; red[tid][5] = ss2;
  __syncthreads();
  if (tid == 0) {
    for (int e = 1; e < 64; e++) {
      mx1 = fmaxf(mx1, red[e][0]); mn1 = fminf(mn1, red[e][1]); ss1 += red[e][2];
      mx2 = fmaxf(mx2, red[e][3]); mn2 = fminf(mn2, red[e][4]); ss2 += red[e][5];
    }
    const float mean = 1.0f / 512.0f;
    const float n = 262144.0f;
    float v1 = (ss1 - n * mean * mean) / (n - 1.0f); float sd1 = sqrtf(fmaxf(v1, 0.f));
    float v2 = (ss2 - n * mean * mean) / (n - 1.0f); float sd2 = sqrtf(fmaxf(v2, 0.f));
    float stv[8] = { mean, sd1, mx1, mn1, mean, sd2, mx2, mn2 };
    float acc = lb2[kb];
    for (int o = 0; o < 16; o++) {
      float h = lb1[kb * 16 + o];
      for (int i = 0; i < 8; i++) h += stv[i] * lw1[(kb * 8 + i) * 16 + o];
      h = fmaxf(h, 0.f);
      acc += h * lw2[kb * 16 + o];
    }
    lam[pair] = 1.0f / (1.0f + __expf(-acc));
  }
}

// ---------------- Stage 1d: epilogue h1 = ob1@Wo - lam*(ob2@Wo) + bo (MFMA) ---
__global__ __launch_bounds__(256) void k_ep(const u16* ob1h, const u16* ob1l,
                                            const u16* ob2h, const u16* ob2l,
                                            const float* lam, const u16* woh, const u16* wol,
                                            fp bo, u16* h1h, u16* h1l) {
  int pair = blockIdx.y; int kb = pair >> 2, b = pair & 3;
  int t0 = blockIdx.x * 16;
  int tid = threadIdx.x;
  int wave = tid >> 6, lane = tid & 63, l15 = lane & 15, quad = lane >> 4;
  float lv = lam[pair];
  long ab = ((long)pair * 512 + t0 + l15) * 64 + quad * 8;
  bf16x8 A1h[2], A1l[2], A2h[2], A2l[2];
#pragma unroll
  for (int kc = 0; kc < 2; kc++) {
    A1h[kc] = *(const bf16x8*)(ob1h + ab + kc * 32);
    A1l[kc] = *(const bf16x8*)(ob1l + ab + kc * 32);
    A2h[kc] = *(const bf16x8*)(ob2h + ab + kc * 32);
    A2l[kc] = *(const bf16x8*)(ob2l + ab + kc * 32);
  }
  const u16* wbh = woh + (long)kb * 8192;
  const u16* wbl = wol + (long)kb * 8192;
#pragma unroll
  for (int cc = 0; cc < 2; cc++) {
    int c = wave * 2 + cc;
    f32x4 d1 = {0.f, 0.f, 0.f, 0.f}, d2 = {0.f, 0.f, 0.f, 0.f};
#pragma unroll
    for (int kc = 0; kc < 2; kc++) {
      long boff = (long)(c * 16 + l15) * 64 + kc * 32 + quad * 8;
      bf16x8 Bh = *(const bf16x8*)(wbh + boff);
      bf16x8 Bl = *(const bf16x8*)(wbl + boff);
      d1 = __builtin_amdgcn_mfma_f32_16x16x32_bf16(A1h[kc], Bh, d1, 0, 0, 0);
      d1 = __builtin_amdgcn_mfma_f32_16x16x32_bf16(A1h[kc], Bl, d1, 0, 0, 0);
      d1 = __builtin_amdgcn_mfma_f32_16x16x32_bf16(A1l[kc], Bh, d1, 0, 0, 0);
      d2 = __builtin_amdgcn_mfma_f32_16x16x32_bf16(A2h[kc], Bh, d2, 0, 0, 0);
      d2 = __builtin_amdgcn_mfma_f32_16x16x32_bf16(A2h[kc], Bl, d2, 0, 0, 0);
      d2 = __builtin_amdgcn_mfma_f32_16x16x32_bf16(A2l[kc], Bh, d2, 0, 0, 0);
    }
    int n = c * 16 + l15;
    float bias = bo[kb * 128 + n];
#pragma unroll
    for (int r = 0; r < 4; r++) {
      int t = t0 + quad * 4 + r;
      float val = d1[r] - lv * d2[r] + bias;
      u16 h, l; splitf(val, h, l);
      long o = ((long)(b * 30 + kb) * 512 + t) * 128 + n;
      h1h[o] = h; h1l[o] = l;
    }
  }
}

// ---------------- Stage 2a: combined conv kernel, packed active taps ----------
// layout [g 0..455][no 128][ni 128]; g = packed (kb, tap)
__global__ __launch_bounds__(256) void k_ck(fp fw, fp cw2, fp cw4, fp cw8,
                                            fp cw16, fp cw32, u16* ckh, u16* ckl) {
  long idx = (long)blockIdx.x * 256 + threadIdx.x;
  int ni = idx & 127;
  int no = (idx >> 7) & 127;
  int g  = (int)(idx >> 14);
  int kb, r;
  if (g < 192)      { kb = g >> 5;                r = g & 31; }
  else if (g < 336) { int gg = g - 192; kb = 6 + (gg >> 4);  r = 8 + (gg & 15); }
  else              { int gg = g - 336; kb = 15 + (gg >> 3); r = 12 + (gg & 7); }
  float f0 = fw[kb * 3 + 0], f1 = fw[kb * 3 + 1], f2 = fw[kb * 3 + 2];
  float mx = fmaxf(f0, fmaxf(f1, f2));
  float e0 = __expf(f0 - mx), e1 = __expf(f1 - mx), e2 = __expf(f2 - mx);
  float zi = 1.0f / (e0 + e1 + e2);
  float sw[3] = { e0 * zi, e1 * zi, e2 * zi };
  int sbase; fp cws[3];
  if (kb < 6)       { sbase = 8; cws[0] = cw8;  cws[1] = cw16; cws[2] = cw32; }
  else if (kb < 15) { sbase = 4; cws[0] = cw4;  cws[1] = cw8;  cws[2] = cw16; }
  else              { sbase = 2; cws[0] = cw2;  cws[1] = cw4;  cws[2] = cw8;  }
  float val = 0.f;
  int rs = r - 16;
#pragma unroll
  for (int j = 0; j < 3; j++) {
    int s = sbase << j;
    int tau = rs + (s >> 1);
    if (tau >= 0 && tau < s) val += sw[j] * cws[j][((long)no * 128 + ni) * s + tau];
  }
  u16 h, l; splitf(val, h, l);
  ckh[idx] = h; ckl[idx] = l;
}

// ---------------- Stage 2b: per-band conv via MFMA (balanced XCD pinning) -----
// grid 1536: xcd = bid&7, s = (bid>>3)>>5, item = (bid>>3)&31.
// Band assignment (arithmetic, per-XCD taps {64,56,...,56}):
//   xcd<6 : s0->xcd, s1->xcd+6, s2->xcd+15, (xcd==0,s3)->29
//   xcd==6: s0,1->12,13 ; s2..4->21,22,23
//   xcd==7: s0->14 ; s1..5->24..28
__global__ __launch_bounds__(256) void k_conv(const u16* h1h, const u16* h1l,
                                              const u16* ckh, const u16* ckl, fp fw,
                                              fp cb2, fp cb4, fp cb8, fp cb16,
                                              fp cb32, u16* h2h, u16* h2l) {
  int bid = blockIdx.x;
  int xcd = bid & 7;
  int slot = bid >> 3;
  int s = slot >> 5;
  int kb = -1;
  if (xcd < 6) {
    if (s == 0) kb = xcd;
    else if (s == 1) kb = xcd + 6;
    else if (s == 2) kb = xcd + 15;
    else if (s == 3 && xcd == 0) kb = 29;
  } else if (xcd == 6) {
    if (s < 2) kb = 12 + s;
    else if (s < 5) kb = 19 + s;
  } else {
    kb = (s == 0) ? 14 : 23 + s;
  }
  if (kb < 0) return;
  int item = slot & 31;
  int b = item >> 3, t0 = (item & 7) * 64;
  int tid = threadIdx.x;
  int wave = tid >> 6, lane = tid & 63, l15 = lane & 15, quad = lane >> 4;
  __shared__ u16 xs_h[96 * 136];
  __shared__ u16 xs_l[96 * 136];
  const u16* xrh = h1h + (long)(b * 30 + kb) * 512 * 128;
  const u16* xrl = h1l + (long)(b * 30 + kb) * 512 * 128;
  bf16x8 zero8 = {0, 0, 0, 0, 0, 0, 0, 0};
  for (int i = tid; i < 1536; i += 256) {
    int row = i >> 4, c8 = (i & 15) << 3;
    int t = t0 - 16 + row;
    bf16x8 vh = zero8, vl = zero8;
    if (t >= 0 && t < 512) {
      vh = *(const bf16x8*)(xrh + (long)t * 128 + c8);
      vl = *(const bf16x8*)(xrl + (long)t * 128 + c8);
    }
    *(bf16x8*)(xs_h + row * 136 + c8) = vh;
    *(bf16x8*)(xs_l + row * 136 + c8) = vl;
  }
  float f0 = fw[kb * 3 + 0], f1 = fw[kb * 3 + 1], f2 = fw[kb * 3 + 2];
  float mx = fmaxf(f0, fmaxf(f1, f2));
  float e0 = __expf(f0 - mx), e1 = __expf(f1 - mx), e2 = __expf(f2 - mx);
  float zi = 1.0f / (e0 + e1 + e2);
  float sw0 = e0 * zi, sw1 = e1 * zi, sw2 = e2 * zi;
  int rlo, rhi, gbase; fp c0, c1, c2;
  if (kb < 6)       { rlo = 0;  rhi = 32; gbase = kb * 32;             c0 = cb8; c1 = cb16; c2 = cb32; }
  else if (kb < 15) { rlo = 8;  rhi = 24; gbase = 192 + (kb - 6) * 16; c0 = cb4; c1 = cb8;  c2 = cb16; }
  else              { rlo = 12; rhi = 20; gbase = 336 + (kb - 15) * 8; c0 = cb2; c1 = cb4;  c2 = cb8;  }
  __syncthreads();
  f32x4 acc[4][2];
#pragma unroll
  for (int mt = 0; mt < 4; mt++) { acc[mt][0] = {0.f,0.f,0.f,0.f}; acc[mt][1] = {0.f,0.f,0.f,0.f}; }
  for (int r = rlo; r < rhi; r++) {
    const u16* wh = ckh + ((long)(gbase + r - rlo) * 128 + wave * 32 + l15) * 128;
    const u16* wl = ckl + ((long)(gbase + r - rlo) * 128 + wave * 32 + l15) * 128;
#pragma unroll
    for (int c = 0; c < 4; c++) {
      int koff = c * 32 + quad * 8;
      bf16x8 Bh0 = *(const bf16x8*)(wh + koff);
      bf16x8 Bh1 = *(const bf16x8*)(wh + 2048 + koff);
      bf16x8 Bl0 = *(const bf16x8*)(wl + koff);
      bf16x8 Bl1 = *(const bf16x8*)(wl + 2048 + koff);
#pragma unroll
      for (int mt = 0; mt < 4; mt++) {
        int arow = mt * 16 + l15 + r;
        bf16x8 Ah = *(const bf16x8*)(xs_h + arow * 136 + koff);
        bf16x8 Al = *(const bf16x8*)(xs_l + arow * 136 + koff);
        acc[mt][0] = __builtin_amdgcn_mfma_f32_16x16x32_bf16(Ah, Bh0, acc[mt][0], 0, 0, 0);
        acc[mt][0] = __builtin_amdgcn_mfma_f32_16x16x32_bf16(Ah, Bl0, acc[mt][0], 0, 0, 0);
        acc[mt][0] = __builtin_amdgcn_mfma_f32_16x16x32_bf16(Al, Bh0, acc[mt][0], 0, 0, 0);
        acc[mt][1] = __builtin_amdgcn_mfma_f32_16x16x32_bf16(Ah, Bh1, acc[mt][1], 0, 0, 0);
        acc[mt][1] = __builtin_amdgcn_mfma_f32_16x16x32_bf16(Ah, Bl1, acc[mt][1], 0, 0, 0);
        acc[mt][1] = __builtin_amdgcn_mfma_f32_16x16x32_bf16(Al, Bh1, acc[mt][1], 0, 0, 0);
      }
    }
  }
  int no0 = wave * 32 + l15;
  float bias0 = sw0 * c0[no0] + sw1 * c1[no0] + sw2 * c2[no0];
  float bias1 = sw0 * c0[no0 + 16] + sw1 * c1[no0 + 16] + sw2 * c2[no0 + 16];
#pragma unroll
  for (int mt = 0; mt < 4; mt++)
#pragma unroll
    for (int reg = 0; reg < 4; reg++) {
      int t = t0 + mt * 16 + quad * 4 + reg;
      long ob = ((long)(b * 512 + t) * 30 + kb) * 128 + no0;
      u16 h, l;
      splitf(acc[mt][0][reg] + bias0, h, l); h2h[ob] = h;      h2l[ob] = l;
      splitf(acc[mt][1][reg] + bias1, h, l); h2h[ob + 16] = h; h2l[ob + 16] = l;
    }
}

// ---------------- Stage 3: fused graph QKV + attention + out GEMM -------------
__global__ __launch_bounds__(256) void k_gattn(const u16* h2h, const u16* h2l,
                                               const u16* gwh, const u16* gwl,
                                               const float* maskw,
                                               fp gbq, fp gbk, fp gbv, fp gbo,
                                               float* out) {
  int m = blockIdx.x; int b = m >> 9; int t = m & 511;
  int tid = threadIdx.x;
  int wave = tid >> 6, lane = tid & 63, l15 = lane & 15, quad = lane >> 4;
  __shared__ float qs[32][136];
  __shared__ float ks[32][136];
  __shared__ float vs[32][136];
  u16* ogs_h = (u16*)&qs[0][0];
  u16* ogs_l = ogs_h + 32 * 136;

  // ---- Phase 1: QKV projection via MFMA ----
  {
    int mtile = wave & 1;
    int c0 = (wave >> 1) * 12;
    long abase0 = (long)m * 30 * 128;
    bf16x8 Ah[4], Al[4];
    bf16x8 zero8 = {0, 0, 0, 0, 0, 0, 0, 0};
    int row = mtile * 16 + l15;
#pragma unroll
    for (int kc = 0; kc < 4; kc++) {
      if (row < 30) {
        Ah[kc] = *(const bf16x8*)(h2h + abase0 + (long)row * 128 + kc * 32 + quad * 8);
        Al[kc] = *(const bf16x8*)(h2l + abase0 + (long)row * 128 + kc * 32 + quad * 8);
      } else { Ah[kc] = zero8; Al[kc] = zero8; }
    }
    for (int cc = 0; cc < 12; cc++) {
      int c = c0 + cc;
      f32x4 d = {0.f, 0.f, 0.f, 0.f};
#pragma unroll
      for (int kc = 0; kc < 4; kc++) {
        long boff = (long)(c * 16 + l15) * 128 + kc * 32 + quad * 8;
        bf16x8 Bh = *(const bf16x8*)(gwh + boff);
        bf16x8 Bl = *(const bf16x8*)(gwl + boff);
        d = __builtin_amdgcn_mfma_f32_16x16x32_bf16(Ah[kc], Bh, d, 0, 0, 0);
        d = __builtin_amdgcn_mfma_f32_16x16x32_bf16(Ah[kc], Bl, d, 0, 0, 0);
        d = __builtin_amdgcn_mfma_f32_16x16x32_bf16(Al[kc], Bh, d, 0, 0, 0);
      }
      int region = c >> 3;
      int ch = (c & 7) * 16 + l15;
      float bias = (region == 0) ? gbq[ch] : (region == 1) ? gbk[ch] : gbv[ch];
      float (*dst)[136] = (region == 0) ? qs : (region == 1) ? ks : vs;
#pragma unroll
      for (int r = 0; r < 4; r++) {
        int rowo = mtile * 16 + quad * 4 + r;
        if (rowo < 30) dst[rowo][ch] = d[r] + bias;
      }
    }
  }
  __syncthreads();

  // ---- Phase 2: 30x30 4-head attention (VALU) ----
  float p[30]; float iZ = 0.f; int hi = 0, ii = 0;
  if (tid < 120) {
    hi = tid / 30; ii = tid % 30;
    int hb = hi * 32;
    float4 qv[8];
#pragma unroll
    for (int dq = 0; dq < 8; dq++) qv[dq] = *(const float4*)&qs[ii][hb + dq * 4];
    float mx = -1e30f;
#pragma unroll
    for (int j = 0; j < 30; j++) {
      float s = 0.f;
      const float4* kr = (const float4*)&ks[j][hb];
#pragma unroll
      for (int dq = 0; dq < 8; dq++) {
        float4 kv = kr[dq];
        s += qv[dq].x * kv.x + qv[dq].y * kv.y + qv[dq].z * kv.z + qv[dq].w * kv.w;
      }
      s *= 0.17677669529663687f;
      p[j] = (maskw[ii * 30 + j] != 0.f) ? s : -1e30f;
      mx = fmaxf(mx, p[j]);
    }
    float Z = 0.f;
#pragma unroll
    for (int j = 0; j < 30; j++) { float e = __expf(p[j] - mx); p[j] = e; Z += e; }
    iZ = 1.0f / Z;
  }
  __syncthreads();
  if (tid < 120) {
    int hb = hi * 32;
#pragma unroll
    for (int dq = 0; dq < 8; dq++) {
      float sx = 0.f, sy = 0.f, sz = 0.f, sw2 = 0.f;
#pragma unroll
      for (int j = 0; j < 30; j++) {
        float4 vv = *(const float4*)&vs[j][hb + dq * 4];
        sx += p[j] * vv.x; sy += p[j] * vv.y; sz += p[j] * vv.z; sw2 += p[j] * vv.w;
      }
      float o4[4] = { sx * iZ, sy * iZ, sz * iZ, sw2 * iZ };
#pragma unroll
      for (int cpt = 0; cpt < 4; cpt++) {
        u16 h, l; splitf(o4[cpt], h, l);
        ogs_h[ii * 136 + hb + dq * 4 + cpt] = h;
        ogs_l[ii * 136 + hb + dq * 4 + cpt] = l;
      }
    }
  }
  __syncthreads();

  // ---- Phase 3: out = og @ gWo + gbo via MFMA ----
  {
    int mtile = wave & 1;
    int nc0 = (wave >> 1) * 4;
    int row = mtile * 16 + l15;
    bf16x8 Ah[4], Al[4];
#pragma unroll
    for (int kc = 0; kc < 4; kc++) {
      Ah[kc] = *(const bf16x8*)(ogs_h + row * 136 + kc * 32 + quad * 8);
      Al[kc] = *(const bf16x8*)(ogs_l + row * 136 + kc * 32 + quad * 8);
    }
    for (int cc = 0; cc < 4; cc++) {
      int nchunk = nc0 + cc;
      f32x4 d = {0.f, 0.f, 0.f, 0.f};
#pragma unroll
      for (int kc = 0; kc < 4; kc++) {
        long boff = (long)(384 + nchunk * 16 + l15) * 128 + kc * 32 + quad * 8;
        bf16x8 Bh = *(const bf16x8*)(gwh + boff);
        bf16x8 Bl = *(const bf16x8*)(gwl + boff);
        d = __builtin_amdgcn_mfma_f32_16x16x32_bf16(Ah[kc], Bh, d, 0, 0, 0);
        d = __builtin_amdgcn_mfma_f32_16x16x32_bf16(Ah[kc], Bl, d, 0, 0, 0);
        d = __builtin_amdgcn_mfma_f32_16x16x32_bf16(Al[kc], Bh, d, 0, 0, 0);
      }
      int n = nchunk * 16 + l15;
      float gb = gbo[n];
      long obase = ((long)(b * 128 + n) * 512 + t) * 30;
#pragma unroll
      for (int r = 0; r < 4; r++) {
        int kbo = mtile * 16 + quad * 4 + r;
        if (kbo < 30) out[obase + kbo] = d[r] + gb;
      }
    }
  }
}

extern "C" void kernel_launch(void* const* d_in, const int* in_sizes, int n_in,
                              void* d_out, int out_size, void* d_ws, size_t ws_size,
                              hipStream_t stream) {
  fp x = (fp)d_in[0], Wq = (fp)d_in[1], Wk = (fp)d_in[2], Wv = (fp)d_in[3],
     Wo = (fp)d_in[4], bo = (fp)d_in[5], lw1 = (fp)d_in[6], lb1 = (fp)d_in[7],
     lw2 = (fp)d_in[8], lb2 = (fp)d_in[9],
     cw2 = (fp)d_in[10], cb2 = (fp)d_in[11], cw4 = (fp)d_in[12], cb4 = (fp)d_in[13],
     cw8 = (fp)d_in[14], cb8 = (fp)d_in[15], cw16 = (fp)d_in[16], cb16 = (fp)d_in[17],
     cw32 = (fp)d_in[18], cb32 = (fp)d_in[19], fw = (fp)d_in[20], be = (fp)d_in[21],
     gWq = (fp)d_in[22], gbq = (fp)d_in[23], gWk = (fp)d_in[24], gbk = (fp)d_in[25],
     gWv = (fp)d_in[26], gbv = (fp)d_in[27], gWo = (fp)d_in[28], gbo = (fp)d_in[29];
  (void)in_sizes; (void)n_in; (void)out_size; (void)ws_size;

  float* ws = (float*)d_ws;
  // ---- workspace map (float offsets), race-free stage-ordered aliasing ----
  u16* qh  = (u16*)ws;                          // [120][512][128]
  u16* ql  = (u16*)(ws + 3932160L);
  u16* kh  = (u16*)(ws + 7864320L);
  u16* kl  = (u16*)(ws + 11796480L);
  u16* vTh = (u16*)(ws + 15728640L);            // [120][64][512]
  u16* vTl = (u16*)(ws + 17694720L);
  float* rowstats = ws + 19660800L;             // [120][512][8]
  float* lam      = ws + 20152320L;             // [120]
  u16* wqkT_h = (u16*)(ws + 20152448L);         // [30][320][128]
  u16* wqkT_l = (u16*)(ws + 20766848L);
  u16* gwT_h  = (u16*)(ws + 21381248L);         // [512][128]
  u16* gwT_l  = (u16*)(ws + 21414016L);
  float* maskw = ws + 21446784L;                // [900]
  u16* woT_h = (u16*)(ws + 21447808L);          // [30][128][64]
  u16* woT_l = (u16*)(ws + 21570688L);
  u16* ob1h = (u16*)(ws + 21693568L);           // [120][512][64] each
  u16* ob1l = (u16*)(ws + 23659648L);
  u16* ob2h = (u16*)(ws + 25625728L);
  u16* ob2l = (u16*)(ws + 27591808L);           // ends 29,557,888 (118.2 MB peak)
  u16* h1h = (u16*)ws;                          // over dead qh/ql (after k_flash)
  u16* h1l = (u16*)(ws + 3932160L);
  u16* h2h = (u16*)(ws + 7864320L);             // over dead kh/kl
  u16* h2l = (u16*)(ws + 11796480L);
  u16* ckh = (u16*)(ws + 21693568L);            // over dead ob* (after k_ep)
  u16* ckl = (u16*)(ws + 25429120L);

  k_adj<<<1, 64, 0, stream>>>(be, maskw);
  k_wt_band<<<dim3(30, 4), 256, 0, stream>>>(Wq, Wk, Wv, Wo, wqkT_h, wqkT_l, woT_h, woT_l);
  k_wt_graph<<<4, 256, 0, stream>>>(gWq, gWk, gWv, gWo, gwT_h, gwT_l);
  k_qkv<<<960, 256, 0, stream>>>(x, wqkT_h, wqkT_l, qh, ql, kh, kl, vTh, vTl);
  k_flash<<<3840, 256, 0, stream>>>(qh, ql, kh, kl, vTh, vTl, rowstats, ob1h, ob1l, ob2h, ob2l);
  k_lam<<<120, 64, 0, stream>>>(rowstats, lw1, lb1, lw2, lb2, lam);
  k_ep<<<dim3(32, 120), 256, 0, stream>>>(ob1h, ob1l, ob2h, ob2l, lam, woT_h, woT_l, bo, h1h, h1l);
  k_ck<<<29184, 256, 0, stream>>>(fw, cw2, cw4, cw8, cw16, cw32, ckh, ckl);
  k_conv<<<1536, 256, 0, stream>>>(h1h, h1l, ckh, ckl, fw, cb2, cb4, cb8, cb16, cb32, h2h, h2l);
  k_gattn<<<2048, 256, 0, stream>>>(h2h, h2l, gwT_h, gwT_l, maskw, gbq, gbk, gbv, gbo, (float*)d_out);
}